// Round 1
// baseline (12685.421 us; speedup 1.0000x reference)
//
#include <hip/hip_runtime.h>
#include <math.h>
#include <limits.h>

#define T_STEPS 32
#define BATCH   16
#define KBEAM   4
#define BKR     64      // BATCH*KBEAM rows
#define HD      512
#define VOC     32000
#define G3      1536    // 3*HD
#define SOS_TOK 1
#define EOS_TOK 2

// ---- workspace layout (float offsets) ----
#define OFF_HCUR   ((size_t)0)
#define OFF_GBUF   (OFF_HCUR + (size_t)BKR*HD)                 // 32768
#define OFF_HNEW   (OFF_GBUF + (size_t)2*BKR*G3)               // +196608
#define OFF_LOGITS (OFF_HNEW + (size_t)T_STEPS*BKR*HD)         // +1048576
#define OFF_ROWOFF (OFF_LOGITS + (size_t)BKR*VOC)              // +2048000
#define OFF_LSE    (OFF_ROWOFF + BKR)
#define OFF_SS     (OFF_LSE + (size_t)T_STEPS*BKR)
#define OFF_SCORES (OFF_SS + BKR)
#define OFF_HNFIN  (OFF_SCORES + (size_t)T_STEPS*BKR)
#define OFF_FEND   (OFF_HNFIN + (size_t)BKR*HD)
// ---- int region (int offsets), base = (int*)(w + OFF_FEND) ----
#define IOFF_INP    0
#define IOFF_PREDS  64
#define IOFF_SYMS   (IOFF_PREDS + T_STEPS*BKR)
#define IOFF_OUTROW (IOFF_SYMS + T_STEPS*BKR)
#define IOFF_CURSYM (IOFF_OUTROW + T_STEPS*BKR)
#define IOFF_RMAP   (IOFF_CURSYM + T_STEPS*BKR)
#define IOFF_END    (IOFF_RMAP + T_STEPS*BATCH)
#define OFF_LOGALL  (OFF_FEND + IOFF_END)    // store-path logits_all (float offset)

// ---- output layout (float offsets into d_out) ----
#define O_OUT0 ((size_t)0)
#define O_HID  ((size_t)T_STEPS*BATCH*VOC)      // 16384000
#define O_SSRT (O_HID + (size_t)BATCH*HD)       // +8192
#define O_LENS (O_SSRT + BATCH*KBEAM)           // +64
#define O_SEQS (O_LENS + BATCH*KBEAM)           // +64 ; size T*B*K = 2048

// ================= GEMM core: C[64 x N-tile] = A(64x512) @ W(512xN) + bias =================
// arow: this thread's A-load row base (row = tid>>2), 512 contiguous floats.
template<bool SUB>
__device__ __forceinline__ void gemm64_core(
    const float* __restrict__ arow,
    const float* __restrict__ W, int N,
    const float* __restrict__ bias,
    int nb,
    float* __restrict__ C, int ldc, int mrow0,
    const float* __restrict__ subm)
{
    __shared__ float As[32][64];
    __shared__ float Ws[32][64];
    const int tid = threadIdx.x;
    const int tm = tid & 15, tn = tid >> 4;
    const int kq  = (tid & 3) * 8;
    const int k_l = tid >> 3, nq = (tid & 7) * 8;
    const int m_l = tid >> 2;

    float acc[4][4];
    #pragma unroll
    for (int r = 0; r < 4; ++r)
        #pragma unroll
        for (int c = 0; c < 4; ++c) acc[r][c] = 0.f;

    for (int k0 = 0; k0 < HD; k0 += 32){
        float4 a0 = *(const float4*)(arow + k0 + kq);
        float4 a1 = *(const float4*)(arow + k0 + kq + 4);
        const float* wp = W + (size_t)(k0 + k_l) * (size_t)N + nb + nq;
        float4 w0 = *(const float4*)wp;
        float4 w1 = *(const float4*)(wp + 4);
        As[kq+0][m_l]=a0.x; As[kq+1][m_l]=a0.y; As[kq+2][m_l]=a0.z; As[kq+3][m_l]=a0.w;
        As[kq+4][m_l]=a1.x; As[kq+5][m_l]=a1.y; As[kq+6][m_l]=a1.z; As[kq+7][m_l]=a1.w;
        *(float4*)&Ws[k_l][nq]   = w0;
        *(float4*)&Ws[k_l][nq+4] = w1;
        __syncthreads();
        #pragma unroll
        for (int kk = 0; kk < 32; ++kk){
            float4 av = *(const float4*)&As[kk][tm*4];
            float4 bv = *(const float4*)&Ws[kk][tn*4];
            float a[4] = {av.x, av.y, av.z, av.w};
            float b[4] = {bv.x, bv.y, bv.z, bv.w};
            #pragma unroll
            for (int r = 0; r < 4; ++r)
                #pragma unroll
                for (int c = 0; c < 4; ++c)
                    acc[r][c] = fmaf(a[r], b[c], acc[r][c]);
        }
        __syncthreads();
    }
    float4 bz = *(const float4*)(bias + nb + tn*4);
    float bb[4] = {bz.x, bz.y, bz.z, bz.w};
    #pragma unroll
    for (int r = 0; r < 4; ++r){
        int m = tm*4 + r;
        float sub = SUB ? subm[m] : 0.f;
        float* cp = C + (size_t)(mrow0 + m) * (size_t)ldc + nb + tn*4;
        #pragma unroll
        for (int c = 0; c < 4; ++c) cp[c] = acc[r][c] + bb[c] - sub;
    }
}

__global__ __launch_bounds__(256) void gemm_gates_kernel(
    const float* __restrict__ E, const int* __restrict__ inp, const float* __restrict__ h_cur,
    const float* __restrict__ W_ih, const float* __restrict__ W_hh,
    const float* __restrict__ b_ih, const float* __restrict__ b_hh,
    float* __restrict__ gbuf)
{
    const int z = blockIdx.z;
    const int m_l = threadIdx.x >> 2;
    const float* arow = z ? (h_cur + (size_t)m_l*HD) : (E + (size_t)inp[m_l]*HD);
    gemm64_core<false>(arow, z ? W_hh : W_ih, G3, z ? b_hh : b_ih, blockIdx.x*64,
                       gbuf + (size_t)z*BKR*G3, G3, 0, nullptr);
}

__global__ __launch_bounds__(256) void gemm_logits_kernel(const float* __restrict__ h_new,
    const float* __restrict__ Wo, const float* __restrict__ bo, float* __restrict__ logits)
{
    const int m_l = threadIdx.x >> 2;
    gemm64_core<false>(h_new + (size_t)m_l*HD, Wo, VOC, bo, blockIdx.x*64, logits, VOC, 0, nullptr);
}

__global__ __launch_bounds__(256) void gemm_final_kernel(const float* __restrict__ h_new_all,
    const int* __restrict__ rmap, const float* __restrict__ lse_all,
    const float* __restrict__ Wo, const float* __restrict__ bo, float* __restrict__ out)
{
    __shared__ float subm[64];
    const int tid = threadIdx.x;
    const int mb = blockIdx.y * 64;
    if (tid < 64) subm[tid] = lse_all[rmap[mb + tid]];
    __syncthreads();
    const int g = rmap[mb + (tid >> 2)];
    gemm64_core<true>(h_new_all + (size_t)g*HD, Wo, VOC, bo, blockIdx.x*64, out, VOC, mb, subm);
}

// ================= GRU combine =================
__global__ void gru_combine_kernel(const float* __restrict__ gbuf, const float* __restrict__ h_cur,
    float* __restrict__ h_new)
{
    int x = blockIdx.x*256 + threadIdx.x;       // 0 .. 64*512
    int i = x >> 9, j = x & 511;
    const float* gi = gbuf + (size_t)i*G3;
    const float* gh = gbuf + (size_t)BKR*G3 + (size_t)i*G3;
    float ir = gi[j], iz = gi[j+512], inn = gi[j+1024];
    float hr = gh[j], hz = gh[j+512], hnv = gh[j+1024];
    float r  = 1.f/(1.f+expf(-(ir+hr)));
    float zz = 1.f/(1.f+expf(-(iz+hz)));
    float n  = tanhf(inn + r*hnv);
    h_new[x] = (1.f - zz)*n + zz*h_cur[x];
}

// ================= per-row max + logsumexp =================
__global__ __launch_bounds__(256) void rowred_kernel(const float* __restrict__ logits,
    const float* __restrict__ ss, float* __restrict__ row_off, float* __restrict__ lse_t)
{
    const int row = blockIdx.x, tid = threadIdx.x;
    const float* lr = logits + (size_t)row*VOC;
    float m = -INFINITY, s = 0.f;
    for (int v = tid; v < VOC; v += 256){
        float x = lr[v];
        if (x > m){ s = s*expf(m - x) + 1.f; m = x; }
        else s += expf(x - m);
    }
    __shared__ float sm[256], sp[256];
    sm[tid]=m; sp[tid]=s; __syncthreads();
    for (int o = 128; o > 0; o >>= 1){
        if (tid < o){
            float m1=sm[tid], m2=sm[tid+o], s1=sp[tid], s2=sp[tid+o];
            float M = fmaxf(m1,m2);
            sp[tid] = s1*expf(m1-M) + s2*expf(m2-M);
            sm[tid] = M;
        }
        __syncthreads();
    }
    if (tid == 0){
        float lse = sm[0] + logf(sp[0]);
        lse_t[row] = lse;
        row_off[row] = ss[row] - lse;   // -inf is fine
    }
}

// ================= top-4 per batch with JAX tie semantics =================
__device__ __forceinline__ void ins4(float* bv, int* bc, float s, int c){
    bool g0 = (s > bv[0]) || (s == bv[0] && c < bc[0]);
    bool g1 = (s > bv[1]) || (s == bv[1] && c < bc[1]);
    bool g2 = (s > bv[2]) || (s == bv[2] && c < bc[2]);
    bool g3 = (s > bv[3]) || (s == bv[3] && c < bc[3]);
    if (g0){ bv[3]=bv[2];bc[3]=bc[2]; bv[2]=bv[1];bc[2]=bc[1]; bv[1]=bv[0];bc[1]=bc[0]; bv[0]=s; bc[0]=c; }
    else if (g1){ bv[3]=bv[2];bc[3]=bc[2]; bv[2]=bv[1];bc[2]=bc[1]; bv[1]=s; bc[1]=c; }
    else if (g2){ bv[3]=bv[2];bc[3]=bc[2]; bv[2]=s; bc[2]=c; }
    else if (g3){ bv[3]=s; bc[3]=c; }
}

__global__ __launch_bounds__(256) void topk_kernel(const float* __restrict__ logits,
    const float* __restrict__ row_off, int t,
    float* __restrict__ scores_all, int* __restrict__ preds_all, int* __restrict__ syms_all,
    float* __restrict__ ss, int* __restrict__ inp,
    const float* __restrict__ h_new, float* __restrict__ h_cur)
{
    const int b = blockIdx.x, tid = threadIdx.x;
    float bv[4] = {-INFINITY,-INFINITY,-INFINITY,-INFINITY};
    int bc[4] = {INT_MAX, INT_MAX, INT_MAX, INT_MAX};
    for (int kl = 0; kl < KBEAM; ++kl){
        const int row = b*KBEAM + kl;
        const float off = row_off[row];
        const float* lr = logits + (size_t)row*VOC;
        for (int v = tid; v < VOC; v += 256)
            ins4(bv, bc, lr[v] + off, kl*VOC + v);
    }
    __shared__ float lv[1024]; __shared__ int lc[1024];
    #pragma unroll
    for (int q = 0; q < 4; ++q){ lv[tid*4+q] = bv[q]; lc[tid*4+q] = bc[q]; }
    __syncthreads();
    __shared__ int spred[KBEAM];
    if (tid < 64){
        float mv[4] = {-INFINITY,-INFINITY,-INFINITY,-INFINITY};
        int mc[4] = {INT_MAX,INT_MAX,INT_MAX,INT_MAX};
        for (int e = tid*16; e < tid*16 + 16; ++e)
            ins4(mv, mc, lv[e], lc[e]);
        for (int o = 1; o < 64; o <<= 1){
            float ov[4]; int oc[4];
            #pragma unroll
            for (int q = 0; q < 4; ++q){ ov[q] = __shfl_xor(mv[q], o, 64); oc[q] = __shfl_xor(mc[q], o, 64); }
            #pragma unroll
            for (int q = 0; q < 4; ++q) ins4(mv, mc, ov[q], oc[q]);
        }
        if (tid == 0){
            #pragma unroll
            for (int u = 0; u < KBEAM; ++u){
                int cand = mc[u]; float val = mv[u];
                int sym = cand % VOC; int pg = b*KBEAM + cand / VOC;
                int slot = b*KBEAM + u;
                scores_all[t*BKR + slot] = val;
                syms_all[t*BKR + slot] = sym;
                preds_all[t*BKR + slot] = pg;
                ss[slot] = (sym == EOS_TOK) ? -INFINITY : val;
                inp[slot] = sym;
                spred[u] = pg;
            }
        }
    }
    __syncthreads();
    for (int x = tid; x < KBEAM*HD; x += 256){
        int u = x >> 9, j = x & 511;
        h_cur[(b*KBEAM+u)*HD + j] = h_new[spred[u]*HD + j];
    }
}

// ================= init =================
__global__ void init_kernel(const float* __restrict__ enc_h, float* __restrict__ h_cur,
    float* __restrict__ ss, int* __restrict__ inp)
{
    const int i = blockIdx.x;
    for (int j = threadIdx.x; j < HD; j += blockDim.x)
        h_cur[i*HD + j] = enc_h[(i & (BATCH-1))*HD + j];   // tile(enc_h,(K,1)): row i = enc_h[i % B]
    if (i == 0 && threadIdx.x < BKR){
        ss[threadIdx.x] = ((threadIdx.x & (KBEAM-1)) == 0) ? 0.f : -INFINITY;
        inp[threadIdx.x] = SOS_TOK;
    }
}

// ================= backtrack (single block, serial-ish, tiny) =================
__global__ __launch_bounds__(256) void backtrack_kernel(
    const float* __restrict__ scores_all, const int* __restrict__ preds_all, const int* __restrict__ syms_all,
    const float* __restrict__ h_new_all, float* __restrict__ hn_fin,
    int* __restrict__ outrow_all, int* __restrict__ cursym_all, int* __restrict__ rmap,
    float* __restrict__ out)
{
    __shared__ int tpred[64]; __shared__ float sfin[64]; __shared__ int lensq[64];
    __shared__ int eosf[BATCH];
    __shared__ int npred[64], orow[64], csym[64];
    __shared__ int cp_slot[64], cp_src[64]; __shared__ int ncopy;
    __shared__ int reidx[64];
    const int tid = threadIdx.x;
    for (int x = tid; x < BKR*HD; x += 256) hn_fin[x] = 0.f;
    if (tid == 0){
        for (int b = 0; b < BATCH; ++b){
            float v[KBEAM]; int used[KBEAM];
            for (int k = 0; k < KBEAM; ++k){ v[k] = scores_all[(T_STEPS-1)*BKR + b*KBEAM + k]; used[k] = 0; }
            for (int u = 0; u < KBEAM; ++u){
                int best = -1; float bvv = 0.f;
                for (int k = 0; k < KBEAM; ++k) if (!used[k] && (best < 0 || v[k] > bvv)){ best = k; bvv = v[k]; }
                used[best] = 1;
                tpred[b*KBEAM+u] = b*KBEAM + best;
                sfin[b*KBEAM+u] = bvv;
                lensq[b*KBEAM+u] = T_STEPS;
            }
            eosf[b] = 0;
        }
    }
    __syncthreads();
    for (int t = T_STEPS-1; t >= 0; --t){
        if (tid == 0){
            int nc = 0;
            for (int i = 0; i < BKR; ++i){
                int tp = tpred[i];
                orow[i]  = tp;
                csym[i]  = syms_all[t*BKR + tp];
                npred[i] = preds_all[t*BKR + tp];
            }
            for (int b = 0; b < BATCH; ++b){
                int eos[KBEAM]; int cnt = 0;
                for (int k = 0; k < KBEAM; ++k) eos[k] = (syms_all[t*BKR + b*KBEAM + k] == EOS_TOK);
                for (int k = 0; k < KBEAM; ++k) if (eos[k]){
                    int higher = 0;
                    for (int k2 = k+1; k2 < KBEAM; ++k2) higher += eos[k2];
                    int occ = eosf[b] + higher;
                    int rk = KBEAM - (occ % KBEAM) - 1;
                    int slot = b*KBEAM + rk;
                    int j = b*KBEAM + k;
                    npred[slot] = preds_all[t*BKR + j];
                    orow[slot]  = j;
                    csym[slot]  = syms_all[t*BKR + j];
                    sfin[slot]  = scores_all[t*BKR + j];
                    lensq[slot] = t + 1;
                    cp_slot[nc] = slot; cp_src[nc] = preds_all[t*BKR + j]; ++nc;
                    ++cnt;
                }
                eosf[b] += cnt;
            }
            for (int i = 0; i < BKR; ++i){
                outrow_all[t*BKR + i] = orow[i];
                cursym_all[t*BKR + i] = csym[i];
                tpred[i] = npred[i];
            }
            ncopy = nc;
        }
        __syncthreads();
        const int nc = ncopy;
        for (int x = tid; x < nc*HD; x += 256){
            int q = x >> 9, j = x & 511;
            hn_fin[cp_slot[q]*HD + j] = h_new_all[(size_t)(t*BKR + cp_src[q])*HD + j];
        }
        __syncthreads();
    }
    if (tid == 0){
        for (int b = 0; b < BATCH; ++b){
            float v[KBEAM]; int used[KBEAM];
            for (int k = 0; k < KBEAM; ++k){ v[k] = sfin[b*KBEAM+k]; used[k] = 0; }
            for (int u = 0; u < KBEAM; ++u){
                int best = -1; float bvv = 0.f;
                for (int k = 0; k < KBEAM; ++k) if (!used[k] && (best < 0 || v[k] > bvv)){ best = k; bvv = v[k]; }
                used[best] = 1;
                reidx[b*KBEAM+u] = best;
                out[O_SSRT + b*KBEAM + u] = bvv;
                out[O_LENS + b*KBEAM + u] = (float)lensq[b*KBEAM + best];
            }
        }
        for (int t2 = 0; t2 < T_STEPS; ++t2)
            for (int b = 0; b < BATCH; ++b)
                rmap[t2*BATCH + b] = t2*BKR + outrow_all[t2*BKR + b*KBEAM + reidx[b*KBEAM]];
    }
    __syncthreads();
    for (int x = tid; x < T_STEPS*BKR; x += 256){
        int t2 = x >> 6, rem = x & 63, b = rem >> 2, k = rem & 3;
        out[O_SEQS + x] = (float)cursym_all[t2*BKR + b*KBEAM + reidx[b*KBEAM + k]];
    }
    for (int x = tid; x < BATCH*HD; x += 256){
        int b = x >> 9, j = x & 511;
        out[O_HID + x] = hn_fin[(b*KBEAM + reidx[b*KBEAM])*HD + j];
    }
}

// ================= store-path output gather =================
__global__ void out_copy_kernel(const float* __restrict__ logits_all, const int* __restrict__ rmap,
    const float* __restrict__ lse_all, float* __restrict__ out)
{
    const int m = blockIdx.x;            // t*BATCH + b
    const int g = rmap[m];               // t*BKR + row
    const float lse = lse_all[g];
    const float* src = logits_all + (size_t)g*VOC;
    float* dst = out + (size_t)m*VOC;
    for (int v = threadIdx.x; v < VOC; v += 256) dst[v] = src[v] - lse;
}

extern "C" void kernel_launch(void* const* d_in, const int* in_sizes, int n_in,
                              void* d_out, int out_size, void* d_ws, size_t ws_size,
                              hipStream_t stream)
{
    const float* enc_h = (const float*)d_in[0];
    const float* E     = (const float*)d_in[1];
    const float* W_ih  = (const float*)d_in[2];
    const float* W_hh  = (const float*)d_in[3];
    const float* b_ih  = (const float*)d_in[4];
    const float* b_hh  = (const float*)d_in[5];
    const float* Wo    = (const float*)d_in[6];
    const float* bo    = (const float*)d_in[7];
    float* out = (float*)d_out;

    float* w = (float*)d_ws;
    float* h_cur          = w + OFF_HCUR;
    float* gbuf           = w + OFF_GBUF;
    float* h_new_all      = w + OFF_HNEW;
    float* logits_scratch = w + OFF_LOGITS;
    float* row_off        = w + OFF_ROWOFF;
    float* lse_all        = w + OFF_LSE;
    float* ss             = w + OFF_SS;
    float* scores_all     = w + OFF_SCORES;
    float* hn_fin         = w + OFF_HNFIN;
    int* wi        = (int*)(w + OFF_FEND);
    int* inp        = wi + IOFF_INP;
    int* preds_all  = wi + IOFF_PREDS;
    int* syms_all   = wi + IOFF_SYMS;
    int* outrow_all = wi + IOFF_OUTROW;
    int* cursym_all = wi + IOFF_CURSYM;
    int* rmap       = wi + IOFF_RMAP;
    float* logits_all = w + OFF_LOGALL;

    const size_t need_store = (OFF_LOGALL + (size_t)T_STEPS*BKR*VOC) * sizeof(float);
    const bool store = (ws_size >= need_store);

    init_kernel<<<dim3(BKR), 256, 0, stream>>>(enc_h, h_cur, ss, inp);
    for (int t = 0; t < T_STEPS; ++t){
        float* logits_t = store ? (logits_all + (size_t)t*BKR*VOC) : logits_scratch;
        float* h_new_t  = h_new_all + (size_t)t*BKR*HD;
        gemm_gates_kernel<<<dim3(G3/64, 1, 2), 256, 0, stream>>>(E, inp, h_cur, W_ih, W_hh, b_ih, b_hh, gbuf);
        gru_combine_kernel<<<dim3(BKR*HD/256), 256, 0, stream>>>(gbuf, h_cur, h_new_t);
        gemm_logits_kernel<<<dim3(VOC/64), 256, 0, stream>>>(h_new_t, Wo, bo, logits_t);
        rowred_kernel<<<dim3(BKR), 256, 0, stream>>>(logits_t, ss, row_off, lse_all + (size_t)t*BKR);
        topk_kernel<<<dim3(BATCH), 256, 0, stream>>>(logits_t, row_off, t, scores_all, preds_all, syms_all,
                                                     ss, inp, h_new_t, h_cur);
    }
    backtrack_kernel<<<dim3(1), 256, 0, stream>>>(scores_all, preds_all, syms_all, h_new_all, hn_fin,
                                                  outrow_all, cursym_all, rmap, out);
    if (store){
        out_copy_kernel<<<dim3(T_STEPS*BATCH), 256, 0, stream>>>(logits_all, rmap, lse_all, out);
    } else {
        gemm_final_kernel<<<dim3(VOC/64, T_STEPS*BATCH/64), 256, 0, stream>>>(h_new_all, rmap, lse_all, Wo, bo, out);
    }
}

// Round 2
// 5751.650 us; speedup vs baseline: 2.2055x; 2.2055x over previous
//
#include <hip/hip_runtime.h>
#include <math.h>
#include <limits.h>

#define T_STEPS 32
#define BATCH   16
#define KBEAM   4
#define BKR     64      // BATCH*KBEAM rows
#define HD      512
#define VOC     32000
#define G3      1536    // 3*HD
#define SOS_TOK 1
#define EOS_TOK 2
#define NSPLIT  16
#define SPLEN   (VOC/NSPLIT)   // 2000

// ---- workspace layout (float offsets) ----
#define OFF_HCUR   ((size_t)0)
#define OFF_GBUF   (OFF_HCUR + (size_t)BKR*HD)
#define OFF_HNEW   (OFF_GBUF + (size_t)2*BKR*G3)
#define OFF_LOGITS (OFF_HNEW + (size_t)T_STEPS*BKR*HD)
#define OFF_LSE    (OFF_LOGITS + (size_t)BKR*VOC)
#define OFF_SS     (OFF_LSE + (size_t)T_STEPS*BKR)
#define OFF_SCORES (OFF_SS + BKR)
#define OFF_HNFIN  (OFF_SCORES + (size_t)T_STEPS*BKR)
#define OFF_PV     (OFF_HNFIN + (size_t)BKR*HD)            // [64][16][4] floats
#define OFF_PM     (OFF_PV + (size_t)BKR*NSPLIT*4)         // [64][16]
#define OFF_PS     (OFF_PM + (size_t)BKR*NSPLIT)           // [64][16]
#define OFF_FEND   (OFF_PS + (size_t)BKR*NSPLIT)
// ---- int region (int offsets), base = (int*)(w + OFF_FEND) ----
#define IOFF_INP    0
#define IOFF_PREDS  64
#define IOFF_SYMS   (IOFF_PREDS + T_STEPS*BKR)
#define IOFF_OUTROW (IOFF_SYMS + T_STEPS*BKR)
#define IOFF_CURSYM (IOFF_OUTROW + T_STEPS*BKR)
#define IOFF_RMAP   (IOFF_CURSYM + T_STEPS*BKR)
#define IOFF_PC     (IOFF_RMAP + T_STEPS*BATCH)
#define IOFF_END    (IOFF_PC + BKR*NSPLIT*4)
#define OFF_LOGALL  (OFF_FEND + IOFF_END)    // store-path logits_all (float offset)

// ---- output layout (float offsets into d_out) ----
#define O_HID  ((size_t)T_STEPS*BATCH*VOC)
#define O_SSRT (O_HID + (size_t)BATCH*HD)
#define O_LENS (O_SSRT + BATCH*KBEAM)
#define O_SEQS (O_LENS + BATCH*KBEAM)

// ================= GEMM core: C[64 x N-tile] = A(64x512) @ W(512xN) + bias =================
template<bool SUB>
__device__ __forceinline__ void gemm64_core(
    const float* __restrict__ arow,
    const float* __restrict__ W, int N,
    const float* __restrict__ bias,
    int nb,
    float* __restrict__ C, int ldc, int mrow0,
    const float* __restrict__ subm)
{
    __shared__ float As[32][64];
    __shared__ float Ws[32][64];
    const int tid = threadIdx.x;
    const int tm = tid & 15, tn = tid >> 4;
    const int kq  = (tid & 3) * 8;
    const int k_l = tid >> 3, nq = (tid & 7) * 8;
    const int m_l = tid >> 2;

    float acc[4][4];
    #pragma unroll
    for (int r = 0; r < 4; ++r)
        #pragma unroll
        for (int c = 0; c < 4; ++c) acc[r][c] = 0.f;

    for (int k0 = 0; k0 < HD; k0 += 32){
        float4 a0 = *(const float4*)(arow + k0 + kq);
        float4 a1 = *(const float4*)(arow + k0 + kq + 4);
        const float* wp = W + (size_t)(k0 + k_l) * (size_t)N + nb + nq;
        float4 w0 = *(const float4*)wp;
        float4 w1 = *(const float4*)(wp + 4);
        As[kq+0][m_l]=a0.x; As[kq+1][m_l]=a0.y; As[kq+2][m_l]=a0.z; As[kq+3][m_l]=a0.w;
        As[kq+4][m_l]=a1.x; As[kq+5][m_l]=a1.y; As[kq+6][m_l]=a1.z; As[kq+7][m_l]=a1.w;
        *(float4*)&Ws[k_l][nq]   = w0;
        *(float4*)&Ws[k_l][nq+4] = w1;
        __syncthreads();
        #pragma unroll
        for (int kk = 0; kk < 32; ++kk){
            float4 av = *(const float4*)&As[kk][tm*4];
            float4 bv = *(const float4*)&Ws[kk][tn*4];
            float a[4] = {av.x, av.y, av.z, av.w};
            float b[4] = {bv.x, bv.y, bv.z, bv.w};
            #pragma unroll
            for (int r = 0; r < 4; ++r)
                #pragma unroll
                for (int c = 0; c < 4; ++c)
                    acc[r][c] = fmaf(a[r], b[c], acc[r][c]);
        }
        __syncthreads();
    }
    float4 bz = *(const float4*)(bias + nb + tn*4);
    float bb[4] = {bz.x, bz.y, bz.z, bz.w};
    #pragma unroll
    for (int r = 0; r < 4; ++r){
        int m = tm*4 + r;
        float sub = SUB ? subm[m] : 0.f;
        float* cp = C + (size_t)(mrow0 + m) * (size_t)ldc + nb + tn*4;
        #pragma unroll
        for (int c = 0; c < 4; ++c) cp[c] = acc[r][c] + bb[c] - sub;
    }
}

__global__ __launch_bounds__(256) void gemm_gates_kernel(
    const float* __restrict__ E, const int* __restrict__ inp, const float* __restrict__ h_cur,
    const float* __restrict__ W_ih, const float* __restrict__ W_hh,
    const float* __restrict__ b_ih, const float* __restrict__ b_hh,
    float* __restrict__ gbuf)
{
    const int z = blockIdx.z;
    const int m_l = threadIdx.x >> 2;
    const float* arow = z ? (h_cur + (size_t)m_l*HD) : (E + (size_t)inp[m_l]*HD);
    gemm64_core<false>(arow, z ? W_hh : W_ih, G3, z ? b_hh : b_ih, blockIdx.x*64,
                       gbuf + (size_t)z*BKR*G3, G3, 0, nullptr);
}

__global__ __launch_bounds__(256) void gemm_logits_kernel(const float* __restrict__ h_new,
    const float* __restrict__ Wo, const float* __restrict__ bo, float* __restrict__ logits)
{
    const int m_l = threadIdx.x >> 2;
    gemm64_core<false>(h_new + (size_t)m_l*HD, Wo, VOC, bo, blockIdx.x*64, logits, VOC, 0, nullptr);
}

__global__ __launch_bounds__(256) void gemm_final_kernel(const float* __restrict__ h_new_all,
    const int* __restrict__ rmap, const float* __restrict__ lse_all,
    const float* __restrict__ Wo, const float* __restrict__ bo, float* __restrict__ out)
{
    __shared__ float subm[64];
    const int tid = threadIdx.x;
    const int mb = blockIdx.y * 64;
    if (tid < 64) subm[tid] = lse_all[rmap[mb + tid]];
    __syncthreads();
    const int g = rmap[mb + (tid >> 2)];
    gemm64_core<true>(h_new_all + (size_t)g*HD, Wo, VOC, bo, blockIdx.x*64, out, VOC, mb, subm);
}

// ================= GRU combine =================
__global__ void gru_combine_kernel(const float* __restrict__ gbuf, const float* __restrict__ h_cur,
    float* __restrict__ h_new)
{
    int x = blockIdx.x*256 + threadIdx.x;
    int i = x >> 9, j = x & 511;
    const float* gi = gbuf + (size_t)i*G3;
    const float* gh = gbuf + (size_t)BKR*G3 + (size_t)i*G3;
    float ir = gi[j], iz = gi[j+512], inn = gi[j+1024];
    float hr = gh[j], hz = gh[j+512], hnv = gh[j+1024];
    float r  = 1.f/(1.f+expf(-(ir+hr)));
    float zz = 1.f/(1.f+expf(-(iz+hz)));
    float n  = tanhf(inn + r*hnv);
    h_new[x] = (1.f - zz)*n + zz*h_cur[x];
}

// ================= top-4 insertion with JAX tie semantics (val desc, cand asc) =================
__device__ __forceinline__ void ins4(float* bv, int* bc, float s, int c){
    bool g0 = (s > bv[0]) || (s == bv[0] && c < bc[0]);
    bool g1 = (s > bv[1]) || (s == bv[1] && c < bc[1]);
    bool g2 = (s > bv[2]) || (s == bv[2] && c < bc[2]);
    bool g3 = (s > bv[3]) || (s == bv[3] && c < bc[3]);
    if (g0){ bv[3]=bv[2];bc[3]=bc[2]; bv[2]=bv[1];bc[2]=bc[1]; bv[1]=bv[0];bc[1]=bc[0]; bv[0]=s; bc[0]=c; }
    else if (g1){ bv[3]=bv[2];bc[3]=bc[2]; bv[2]=bv[1];bc[2]=bc[1]; bv[1]=s; bc[1]=c; }
    else if (g2){ bv[3]=bv[2];bc[3]=bc[2]; bv[2]=s; bc[2]=c; }
    else if (g3){ bv[3]=s; bc[3]=c; }
}

// ================= phase A: per (row, split) raw-logit top-4 + lse partial =================
__global__ __launch_bounds__(256) void topk_phase_a(const float* __restrict__ logits,
    float* __restrict__ pv, int* __restrict__ pc, float* __restrict__ pm, float* __restrict__ ps)
{
    const int split = blockIdx.x, row = blockIdx.y;
    const int tid = threadIdx.x;
    const float* lr = logits + (size_t)row*VOC;
    const int v0 = split*SPLEN;
    float m = -INFINITY, s = 0.f;
    float bv[4] = {-INFINITY,-INFINITY,-INFINITY,-INFINITY};
    int bc[4] = {INT_MAX,INT_MAX,INT_MAX,INT_MAX};
    for (int v = v0 + tid; v < v0 + SPLEN; v += 256){
        float x = lr[v];
        if (x > m){ s = s*expf(m - x) + 1.f; m = x; }
        else s += expf(x - m);
        ins4(bv, bc, x, v);
    }
    // wave butterfly: top4 + (m,s)
    #pragma unroll
    for (int o = 1; o < 64; o <<= 1){
        float ov[4]; int oc[4];
        #pragma unroll
        for (int q = 0; q < 4; ++q){ ov[q] = __shfl_xor(bv[q], o, 64); oc[q] = __shfl_xor(bc[q], o, 64); }
        #pragma unroll
        for (int q = 0; q < 4; ++q) ins4(bv, bc, ov[q], oc[q]);
        float m2 = __shfl_xor(m, o, 64), s2 = __shfl_xor(s, o, 64);
        float M = fmaxf(m, m2);
        s = s*expf(m - M) + s2*expf(m2 - M);
        m = M;
    }
    __shared__ float wv[16]; __shared__ int wc[16];
    __shared__ float wm[4], wsum[4];
    const int lane = tid & 63, wave = tid >> 6;
    if (lane == 0){
        #pragma unroll
        for (int q = 0; q < 4; ++q){ wv[wave*4+q] = bv[q]; wc[wave*4+q] = bc[q]; }
        wm[wave] = m; wsum[wave] = s;
    }
    __syncthreads();
    if (tid == 0){
        float fv[4] = {-INFINITY,-INFINITY,-INFINITY,-INFINITY};
        int fc[4] = {INT_MAX,INT_MAX,INT_MAX,INT_MAX};
        #pragma unroll
        for (int e = 0; e < 16; ++e) ins4(fv, fc, wv[e], wc[e]);
        float M = wm[0], S = wsum[0];
        #pragma unroll
        for (int q = 1; q < 4; ++q){
            float M2 = fmaxf(M, wm[q]);
            S = S*expf(M - M2) + wsum[q]*expf(wm[q] - M2);
            M = M2;
        }
        const int idx = row*NSPLIT + split;
        #pragma unroll
        for (int q = 0; q < 4; ++q){ pv[idx*4+q] = fv[q]; pc[idx*4+q] = fc[q]; }
        pm[idx] = M; ps[idx] = S;
    }
}

// ================= phase B: merge, apply ss-lse, pick batch top-4, advance state =================
__global__ __launch_bounds__(256) void topk_phase_b(
    const float* __restrict__ pv, const int* __restrict__ pc,
    const float* __restrict__ pm, const float* __restrict__ ps,
    int t,
    float* __restrict__ scores_all, int* __restrict__ preds_all, int* __restrict__ syms_all,
    float* __restrict__ ss, int* __restrict__ inp, float* __restrict__ lse_all,
    const float* __restrict__ h_new, float* __restrict__ h_cur)
{
    const int b = blockIdx.x, tid = threadIdx.x;
    __shared__ int spred[KBEAM];
    if (tid == 0){
        float gv[4] = {-INFINITY,-INFINITY,-INFINITY,-INFINITY};
        int gc[4] = {INT_MAX,INT_MAX,INT_MAX,INT_MAX};
        for (int kl = 0; kl < KBEAM; ++kl){
            const int row = b*KBEAM + kl;
            float M = pm[row*NSPLIT], S = ps[row*NSPLIT];
            for (int sp = 1; sp < NSPLIT; ++sp){
                float m2 = pm[row*NSPLIT+sp], s2 = ps[row*NSPLIT+sp];
                float M2 = fmaxf(M, m2);
                S = S*expf(M - M2) + s2*expf(m2 - M2);
                M = M2;
            }
            float lse = M + logf(S);
            lse_all[t*BKR + row] = lse;
            float off = ss[row] - lse;
            if (off == -INFINITY){
                // all candidates -inf: JAX top_k yields smallest indices 0..3
                #pragma unroll
                for (int q = 0; q < 4; ++q) ins4(gv, gc, -INFINITY, kl*VOC + q);
            } else {
                float rv[4] = {-INFINITY,-INFINITY,-INFINITY,-INFINITY};
                int rc[4] = {INT_MAX,INT_MAX,INT_MAX,INT_MAX};
                for (int e = row*NSPLIT*4; e < (row+1)*NSPLIT*4; ++e)
                    ins4(rv, rc, pv[e], pc[e]);
                #pragma unroll
                for (int q = 0; q < 4; ++q) ins4(gv, gc, rv[q] + off, kl*VOC + rc[q]);
            }
        }
        #pragma unroll
        for (int u = 0; u < KBEAM; ++u){
            int cand = gc[u]; float val = gv[u];
            int sym = cand % VOC; int pg = b*KBEAM + cand / VOC;
            int slot = b*KBEAM + u;
            scores_all[t*BKR + slot] = val;
            syms_all[t*BKR + slot] = sym;
            preds_all[t*BKR + slot] = pg;
            ss[slot] = (sym == EOS_TOK) ? -INFINITY : val;
            inp[slot] = sym;
            spred[u] = pg;
        }
    }
    __syncthreads();
    for (int x = tid; x < KBEAM*HD; x += 256){
        int u = x >> 9, j = x & 511;
        h_cur[(b*KBEAM+u)*HD + j] = h_new[spred[u]*HD + j];
    }
}

// ================= init =================
__global__ void init_kernel(const float* __restrict__ enc_h, float* __restrict__ h_cur,
    float* __restrict__ ss, int* __restrict__ inp)
{
    const int i = blockIdx.x;
    for (int j = threadIdx.x; j < HD; j += blockDim.x)
        h_cur[i*HD + j] = enc_h[(i & (BATCH-1))*HD + j];
    if (i == 0 && threadIdx.x < BKR){
        ss[threadIdx.x] = ((threadIdx.x & (KBEAM-1)) == 0) ? 0.f : -INFINITY;
        inp[threadIdx.x] = SOS_TOK;
    }
}

// ================= backtrack (single block, tiny) =================
__global__ __launch_bounds__(256) void backtrack_kernel(
    const float* __restrict__ scores_all, const int* __restrict__ preds_all, const int* __restrict__ syms_all,
    const float* __restrict__ h_new_all, float* __restrict__ hn_fin,
    int* __restrict__ outrow_all, int* __restrict__ cursym_all, int* __restrict__ rmap,
    float* __restrict__ out)
{
    __shared__ int tpred[64]; __shared__ float sfin[64]; __shared__ int lensq[64];
    __shared__ int eosf[BATCH];
    __shared__ int npred[64], orow[64], csym[64];
    __shared__ int cp_slot[64], cp_src[64]; __shared__ int ncopy;
    __shared__ int reidx[64];
    const int tid = threadIdx.x;
    for (int x = tid; x < BKR*HD; x += 256) hn_fin[x] = 0.f;
    if (tid == 0){
        for (int b = 0; b < BATCH; ++b){
            float v[KBEAM]; int used[KBEAM];
            for (int k = 0; k < KBEAM; ++k){ v[k] = scores_all[(T_STEPS-1)*BKR + b*KBEAM + k]; used[k] = 0; }
            for (int u = 0; u < KBEAM; ++u){
                int best = -1; float bvv = 0.f;
                for (int k = 0; k < KBEAM; ++k) if (!used[k] && (best < 0 || v[k] > bvv)){ best = k; bvv = v[k]; }
                used[best] = 1;
                tpred[b*KBEAM+u] = b*KBEAM + best;
                sfin[b*KBEAM+u] = bvv;
                lensq[b*KBEAM+u] = T_STEPS;
            }
            eosf[b] = 0;
        }
    }
    __syncthreads();
    for (int t = T_STEPS-1; t >= 0; --t){
        if (tid == 0){
            int nc = 0;
            for (int i = 0; i < BKR; ++i){
                int tp = tpred[i];
                orow[i]  = tp;
                csym[i]  = syms_all[t*BKR + tp];
                npred[i] = preds_all[t*BKR + tp];
            }
            for (int b = 0; b < BATCH; ++b){
                int eos[KBEAM]; int cnt = 0;
                for (int k = 0; k < KBEAM; ++k) eos[k] = (syms_all[t*BKR + b*KBEAM + k] == EOS_TOK);
                for (int k = 0; k < KBEAM; ++k) if (eos[k]){
                    int higher = 0;
                    for (int k2 = k+1; k2 < KBEAM; ++k2) higher += eos[k2];
                    int occ = eosf[b] + higher;
                    int rk = KBEAM - (occ % KBEAM) - 1;
                    int slot = b*KBEAM + rk;
                    int j = b*KBEAM + k;
                    npred[slot] = preds_all[t*BKR + j];
                    orow[slot]  = j;
                    csym[slot]  = syms_all[t*BKR + j];
                    sfin[slot]  = scores_all[t*BKR + j];
                    lensq[slot] = t + 1;
                    cp_slot[nc] = slot; cp_src[nc] = preds_all[t*BKR + j]; ++nc;
                    ++cnt;
                }
                eosf[b] += cnt;
            }
            for (int i = 0; i < BKR; ++i){
                outrow_all[t*BKR + i] = orow[i];
                cursym_all[t*BKR + i] = csym[i];
                tpred[i] = npred[i];
            }
            ncopy = nc;
        }
        __syncthreads();
        const int nc = ncopy;
        for (int x = tid; x < nc*HD; x += 256){
            int q = x >> 9, j = x & 511;
            hn_fin[cp_slot[q]*HD + j] = h_new_all[(size_t)(t*BKR + cp_src[q])*HD + j];
        }
        __syncthreads();
    }
    if (tid == 0){
        for (int b = 0; b < BATCH; ++b){
            float v[KBEAM]; int used[KBEAM];
            for (int k = 0; k < KBEAM; ++k){ v[k] = sfin[b*KBEAM+k]; used[k] = 0; }
            for (int u = 0; u < KBEAM; ++u){
                int best = -1; float bvv = 0.f;
                for (int k = 0; k < KBEAM; ++k) if (!used[k] && (best < 0 || v[k] > bvv)){ best = k; bvv = v[k]; }
                used[best] = 1;
                reidx[b*KBEAM+u] = best;
                out[O_SSRT + b*KBEAM + u] = bvv;
                out[O_LENS + b*KBEAM + u] = (float)lensq[b*KBEAM + best];
            }
        }
        for (int t2 = 0; t2 < T_STEPS; ++t2)
            for (int b = 0; b < BATCH; ++b)
                rmap[t2*BATCH + b] = t2*BKR + outrow_all[t2*BKR + b*KBEAM + reidx[b*KBEAM]];
    }
    __syncthreads();
    for (int x = tid; x < T_STEPS*BKR; x += 256){
        int t2 = x >> 6, rem = x & 63, b = rem >> 2, k = rem & 3;
        out[O_SEQS + x] = (float)cursym_all[t2*BKR + b*KBEAM + reidx[b*KBEAM + k]];
    }
    for (int x = tid; x < BATCH*HD; x += 256){
        int b = x >> 9, j = x & 511;
        out[O_HID + x] = hn_fin[(b*KBEAM + reidx[b*KBEAM])*HD + j];
    }
}

// ================= store-path output gather =================
__global__ void out_copy_kernel(const float* __restrict__ logits_all, const int* __restrict__ rmap,
    const float* __restrict__ lse_all, float* __restrict__ out)
{
    const int m = blockIdx.x;
    const int g = rmap[m];
    const float lse = lse_all[g];
    const float* src = logits_all + (size_t)g*VOC;
    float* dst = out + (size_t)m*VOC;
    for (int v = threadIdx.x; v < VOC; v += 256) dst[v] = src[v] - lse;
}

extern "C" void kernel_launch(void* const* d_in, const int* in_sizes, int n_in,
                              void* d_out, int out_size, void* d_ws, size_t ws_size,
                              hipStream_t stream)
{
    const float* enc_h = (const float*)d_in[0];
    const float* E     = (const float*)d_in[1];
    const float* W_ih  = (const float*)d_in[2];
    const float* W_hh  = (const float*)d_in[3];
    const float* b_ih  = (const float*)d_in[4];
    const float* b_hh  = (const float*)d_in[5];
    const float* Wo    = (const float*)d_in[6];
    const float* bo    = (const float*)d_in[7];
    float* out = (float*)d_out;

    float* w = (float*)d_ws;
    float* h_cur          = w + OFF_HCUR;
    float* gbuf           = w + OFF_GBUF;
    float* h_new_all      = w + OFF_HNEW;
    float* logits_scratch = w + OFF_LOGITS;
    float* lse_all        = w + OFF_LSE;
    float* ss             = w + OFF_SS;
    float* scores_all     = w + OFF_SCORES;
    float* hn_fin         = w + OFF_HNFIN;
    float* pv             = w + OFF_PV;
    float* pm             = w + OFF_PM;
    float* ps             = w + OFF_PS;
    int* wi        = (int*)(w + OFF_FEND);
    int* inp        = wi + IOFF_INP;
    int* preds_all  = wi + IOFF_PREDS;
    int* syms_all   = wi + IOFF_SYMS;
    int* outrow_all = wi + IOFF_OUTROW;
    int* cursym_all = wi + IOFF_CURSYM;
    int* rmap       = wi + IOFF_RMAP;
    int* pc         = wi + IOFF_PC;
    float* logits_all = w + OFF_LOGALL;

    const size_t need_store = (OFF_LOGALL + (size_t)T_STEPS*BKR*VOC) * sizeof(float);
    const bool store = (ws_size >= need_store);

    init_kernel<<<dim3(BKR), 256, 0, stream>>>(enc_h, h_cur, ss, inp);
    for (int t = 0; t < T_STEPS; ++t){
        float* logits_t = store ? (logits_all + (size_t)t*BKR*VOC) : logits_scratch;
        float* h_new_t  = h_new_all + (size_t)t*BKR*HD;
        gemm_gates_kernel<<<dim3(G3/64, 1, 2), 256, 0, stream>>>(E, inp, h_cur, W_ih, W_hh, b_ih, b_hh, gbuf);
        gru_combine_kernel<<<dim3(BKR*HD/256), 256, 0, stream>>>(gbuf, h_cur, h_new_t);
        gemm_logits_kernel<<<dim3(VOC/64), 256, 0, stream>>>(h_new_t, Wo, bo, logits_t);
        topk_phase_a<<<dim3(NSPLIT, BKR), 256, 0, stream>>>(logits_t, pv, pc, pm, ps);
        topk_phase_b<<<dim3(BATCH), 256, 0, stream>>>(pv, pc, pm, ps, t, scores_all, preds_all, syms_all,
                                                      ss, inp, lse_all, h_new_t, h_cur);
    }
    backtrack_kernel<<<dim3(1), 256, 0, stream>>>(scores_all, preds_all, syms_all, h_new_all, hn_fin,
                                                  outrow_all, cursym_all, rmap, out);
    if (store){
        out_copy_kernel<<<dim3(T_STEPS*BATCH), 256, 0, stream>>>(logits_all, rmap, lse_all, out);
    } else {
        gemm_final_kernel<<<dim3(VOC/64, T_STEPS*BATCH/64), 256, 0, stream>>>(h_new_all, rmap, lse_all, Wo, bo, out);
    }
}

// Round 3
// 3483.333 us; speedup vs baseline: 3.6417x; 1.6512x over previous
//
#include <hip/hip_runtime.h>
#include <math.h>
#include <limits.h>

#define T_STEPS 32
#define BATCH   16
#define KBEAM   4
#define BKR     64      // BATCH*KBEAM rows
#define HD      512
#define VOC     32000
#define G3      1536    // 3*HD
#define SOS_TOK 1
#define EOS_TOK 2
#define NSPLIT  16
#define SPLEN   (VOC/NSPLIT)   // 2000

// ---- workspace layout (float offsets) ----
#define OFF_HCUR   ((size_t)0)
#define OFF_GBUF   (OFF_HCUR + (size_t)BKR*HD)
#define OFF_HNEW   (OFF_GBUF + (size_t)2*BKR*G3)
#define OFF_LOGITS (OFF_HNEW + (size_t)T_STEPS*BKR*HD)
#define OFF_LSE    (OFF_LOGITS + (size_t)BKR*VOC)
#define OFF_SS     (OFF_LSE + (size_t)T_STEPS*BKR)
#define OFF_SCORES (OFF_SS + BKR)
#define OFF_HNFIN  (OFF_SCORES + (size_t)T_STEPS*BKR)
#define OFF_PV     (OFF_HNFIN + (size_t)BKR*HD)            // [64][16][4] floats
#define OFF_PM     (OFF_PV + (size_t)BKR*NSPLIT*4)         // [64][16]
#define OFF_PS     (OFF_PM + (size_t)BKR*NSPLIT)           // [64][16]
#define OFF_FEND   (OFF_PS + (size_t)BKR*NSPLIT)
// ---- int region (int offsets), base = (int*)(w + OFF_FEND) ----
#define IOFF_INP    0
#define IOFF_PREDS  64
#define IOFF_SYMS   (IOFF_PREDS + T_STEPS*BKR)
#define IOFF_RMAP   (IOFF_SYMS + T_STEPS*BKR)
#define IOFF_PC     (IOFF_RMAP + T_STEPS*BATCH)
#define IOFF_END    (IOFF_PC + BKR*NSPLIT*4)
#define OFF_LOGALL  (OFF_FEND + IOFF_END)    // store-path logits_all (float offset)

// ---- output layout (float offsets into d_out) ----
#define O_HID  ((size_t)T_STEPS*BATCH*VOC)
#define O_SSRT (O_HID + (size_t)BATCH*HD)
#define O_LENS (O_SSRT + BATCH*KBEAM)
#define O_SEQS (O_LENS + BATCH*KBEAM)

// ================= GEMM core: C[64 x N-tile] = A(64x512) @ W(512xN) + bias =================
template<bool SUB>
__device__ __forceinline__ void gemm64_core(
    const float* __restrict__ arow,
    const float* __restrict__ W, int N,
    const float* __restrict__ bias,
    int nb,
    float* __restrict__ C, int ldc, int mrow0,
    const float* __restrict__ subm)
{
    __shared__ float As[32][64];
    __shared__ float Ws[32][64];
    const int tid = threadIdx.x;
    const int tm = tid & 15, tn = tid >> 4;
    const int kq  = (tid & 3) * 8;
    const int k_l = tid >> 3, nq = (tid & 7) * 8;
    const int m_l = tid >> 2;

    float acc[4][4];
    #pragma unroll
    for (int r = 0; r < 4; ++r)
        #pragma unroll
        for (int c = 0; c < 4; ++c) acc[r][c] = 0.f;

    for (int k0 = 0; k0 < HD; k0 += 32){
        float4 a0 = *(const float4*)(arow + k0 + kq);
        float4 a1 = *(const float4*)(arow + k0 + kq + 4);
        const float* wp = W + (size_t)(k0 + k_l) * (size_t)N + nb + nq;
        float4 w0 = *(const float4*)wp;
        float4 w1 = *(const float4*)(wp + 4);
        As[kq+0][m_l]=a0.x; As[kq+1][m_l]=a0.y; As[kq+2][m_l]=a0.z; As[kq+3][m_l]=a0.w;
        As[kq+4][m_l]=a1.x; As[kq+5][m_l]=a1.y; As[kq+6][m_l]=a1.z; As[kq+7][m_l]=a1.w;
        *(float4*)&Ws[k_l][nq]   = w0;
        *(float4*)&Ws[k_l][nq+4] = w1;
        __syncthreads();
        #pragma unroll
        for (int kk = 0; kk < 32; ++kk){
            float4 av = *(const float4*)&As[kk][tm*4];
            float4 bv = *(const float4*)&Ws[kk][tn*4];
            float a[4] = {av.x, av.y, av.z, av.w};
            float b[4] = {bv.x, bv.y, bv.z, bv.w};
            #pragma unroll
            for (int r = 0; r < 4; ++r)
                #pragma unroll
                for (int c = 0; c < 4; ++c)
                    acc[r][c] = fmaf(a[r], b[c], acc[r][c]);
        }
        __syncthreads();
    }
    float4 bz = *(const float4*)(bias + nb + tn*4);
    float bb[4] = {bz.x, bz.y, bz.z, bz.w};
    #pragma unroll
    for (int r = 0; r < 4; ++r){
        int m = tm*4 + r;
        float sub = SUB ? subm[m] : 0.f;
        float* cp = C + (size_t)(mrow0 + m) * (size_t)ldc + nb + tn*4;
        #pragma unroll
        for (int c = 0; c < 4; ++c) cp[c] = acc[r][c] + bb[c] - sub;
    }
}

__global__ __launch_bounds__(256) void gemm_gates_kernel(
    const float* __restrict__ E, const int* __restrict__ inp, const float* __restrict__ h_cur,
    const float* __restrict__ W_ih, const float* __restrict__ W_hh,
    const float* __restrict__ b_ih, const float* __restrict__ b_hh,
    float* __restrict__ gbuf)
{
    const int z = blockIdx.z;
    const int m_l = threadIdx.x >> 2;
    const float* arow = z ? (h_cur + (size_t)m_l*HD) : (E + (size_t)inp[m_l]*HD);
    gemm64_core<false>(arow, z ? W_hh : W_ih, G3, z ? b_hh : b_ih, blockIdx.x*64,
                       gbuf + (size_t)z*BKR*G3, G3, 0, nullptr);
}

__global__ __launch_bounds__(256) void gemm_logits_kernel(const float* __restrict__ h_new,
    const float* __restrict__ Wo, const float* __restrict__ bo, float* __restrict__ logits)
{
    const int m_l = threadIdx.x >> 2;
    gemm64_core<false>(h_new + (size_t)m_l*HD, Wo, VOC, bo, blockIdx.x*64, logits, VOC, 0, nullptr);
}

__global__ __launch_bounds__(256) void gemm_final_kernel(const float* __restrict__ h_new_all,
    const int* __restrict__ rmap, const float* __restrict__ lse_all,
    const float* __restrict__ Wo, const float* __restrict__ bo, float* __restrict__ out)
{
    __shared__ float subm[64];
    const int tid = threadIdx.x;
    const int mb = blockIdx.y * 64;
    if (tid < 64) subm[tid] = lse_all[rmap[mb + tid]];
    __syncthreads();
    const int g = rmap[mb + (tid >> 2)];
    gemm64_core<true>(h_new_all + (size_t)g*HD, Wo, VOC, bo, blockIdx.x*64, out, VOC, mb, subm);
}

// ================= GRU combine =================
__global__ void gru_combine_kernel(const float* __restrict__ gbuf, const float* __restrict__ h_cur,
    float* __restrict__ h_new)
{
    int x = blockIdx.x*256 + threadIdx.x;
    int i = x >> 9, j = x & 511;
    const float* gi = gbuf + (size_t)i*G3;
    const float* gh = gbuf + (size_t)BKR*G3 + (size_t)i*G3;
    float ir = gi[j], iz = gi[j+512], inn = gi[j+1024];
    float hr = gh[j], hz = gh[j+512], hnv = gh[j+1024];
    float r  = 1.f/(1.f+expf(-(ir+hr)));
    float zz = 1.f/(1.f+expf(-(iz+hz)));
    float n  = tanhf(inn + r*hnv);
    h_new[x] = (1.f - zz)*n + zz*h_cur[x];
}

// ================= top-4 insertion with JAX tie semantics (val desc, cand asc) =================
__device__ __forceinline__ void ins4(float* bv, int* bc, float s, int c){
    bool g0 = (s > bv[0]) || (s == bv[0] && c < bc[0]);
    bool g1 = (s > bv[1]) || (s == bv[1] && c < bc[1]);
    bool g2 = (s > bv[2]) || (s == bv[2] && c < bc[2]);
    bool g3 = (s > bv[3]) || (s == bv[3] && c < bc[3]);
    if (g0){ bv[3]=bv[2];bc[3]=bc[2]; bv[2]=bv[1];bc[2]=bc[1]; bv[1]=bv[0];bc[1]=bc[0]; bv[0]=s; bc[0]=c; }
    else if (g1){ bv[3]=bv[2];bc[3]=bc[2]; bv[2]=bv[1];bc[2]=bc[1]; bv[1]=s; bc[1]=c; }
    else if (g2){ bv[3]=bv[2];bc[3]=bc[2]; bv[2]=s; bc[2]=c; }
    else if (g3){ bv[3]=s; bc[3]=c; }
}

// ================= phase A: per (row, split) raw-logit top-4 + lse partial =================
__global__ __launch_bounds__(256) void topk_phase_a(const float* __restrict__ logits,
    float* __restrict__ pv, int* __restrict__ pc, float* __restrict__ pm, float* __restrict__ ps)
{
    const int split = blockIdx.x, row = blockIdx.y;
    const int tid = threadIdx.x;
    const float* lr = logits + (size_t)row*VOC;
    const int v0 = split*SPLEN;
    float m = -INFINITY, s = 0.f;
    float bv[4] = {-INFINITY,-INFINITY,-INFINITY,-INFINITY};
    int bc[4] = {INT_MAX,INT_MAX,INT_MAX,INT_MAX};
    for (int v = v0 + tid; v < v0 + SPLEN; v += 256){
        float x = lr[v];
        if (x > m){ s = s*expf(m - x) + 1.f; m = x; }
        else s += expf(x - m);
        ins4(bv, bc, x, v);
    }
    #pragma unroll
    for (int o = 1; o < 64; o <<= 1){
        float ov[4]; int oc[4];
        #pragma unroll
        for (int q = 0; q < 4; ++q){ ov[q] = __shfl_xor(bv[q], o, 64); oc[q] = __shfl_xor(bc[q], o, 64); }
        #pragma unroll
        for (int q = 0; q < 4; ++q) ins4(bv, bc, ov[q], oc[q]);
        float m2 = __shfl_xor(m, o, 64), s2 = __shfl_xor(s, o, 64);
        float M = fmaxf(m, m2);
        s = s*expf(m - M) + s2*expf(m2 - M);
        m = M;
    }
    __shared__ float wv[16]; __shared__ int wc[16];
    __shared__ float wm[4], wsum[4];
    const int lane = tid & 63, wave = tid >> 6;
    if (lane == 0){
        #pragma unroll
        for (int q = 0; q < 4; ++q){ wv[wave*4+q] = bv[q]; wc[wave*4+q] = bc[q]; }
        wm[wave] = m; wsum[wave] = s;
    }
    __syncthreads();
    if (tid == 0){
        float fv[4] = {-INFINITY,-INFINITY,-INFINITY,-INFINITY};
        int fc[4] = {INT_MAX,INT_MAX,INT_MAX,INT_MAX};
        #pragma unroll
        for (int e = 0; e < 16; ++e) ins4(fv, fc, wv[e], wc[e]);
        float M = wm[0], S = wsum[0];
        #pragma unroll
        for (int q = 1; q < 4; ++q){
            float M2 = fmaxf(M, wm[q]);
            S = S*expf(M - M2) + wsum[q]*expf(wm[q] - M2);
            M = M2;
        }
        const int idx = row*NSPLIT + split;
        #pragma unroll
        for (int q = 0; q < 4; ++q){ pv[idx*4+q] = fv[q]; pc[idx*4+q] = fc[q]; }
        pm[idx] = M; ps[idx] = S;
    }
}

// ================= phase B: parallel merge, apply ss-lse, batch top-4, advance state ==========
__global__ __launch_bounds__(256) void topk_phase_b(
    const float* __restrict__ pv, const int* __restrict__ pc,
    const float* __restrict__ pm, const float* __restrict__ ps,
    int t,
    float* __restrict__ scores_all, int* __restrict__ preds_all, int* __restrict__ syms_all,
    float* __restrict__ ss, int* __restrict__ inp, float* __restrict__ lse_all,
    const float* __restrict__ h_new, float* __restrict__ h_cur)
{
    const int b = blockIdx.x, tid = threadIdx.x;
    const int wave = tid >> 6, lane = tid & 63;
    const int row = b*KBEAM + wave;          // wave w handles beam-row w

    // --- per-row top-4 merge: 64 (split,q) entries -> 64 lanes, butterfly ---
    float bv[4]; int bc[4];
    bv[0] = pv[row*64 + lane]; bc[0] = pc[row*64 + lane];
    bv[1] = bv[2] = bv[3] = -INFINITY;
    bc[1] = bc[2] = bc[3] = INT_MAX;
    #pragma unroll
    for (int o = 1; o < 64; o <<= 1){
        float ov[4]; int oc[4];
        #pragma unroll
        for (int q = 0; q < 4; ++q){ ov[q] = __shfl_xor(bv[q], o, 64); oc[q] = __shfl_xor(bc[q], o, 64); }
        #pragma unroll
        for (int q = 0; q < 4; ++q) ins4(bv, bc, ov[q], oc[q]);
    }
    // --- lse merge: 16 split partials on lanes 0..15, width-16 butterfly ---
    float m = (lane < NSPLIT) ? pm[row*NSPLIT + lane] : -INFINITY;
    float s = (lane < NSPLIT) ? ps[row*NSPLIT + lane] : 0.f;
    #pragma unroll
    for (int o = 1; o < 16; o <<= 1){
        float m2 = __shfl_xor(m, o, 16), s2 = __shfl_xor(s, o, 16);
        float M = fmaxf(m, m2);
        s = s*expf(m - M) + s2*expf(m2 - M);
        m = M;
    }
    __shared__ float rtv[KBEAM][4]; __shared__ int rtc[KBEAM][4];
    __shared__ float rlse[KBEAM];
    if (lane == 0){
        #pragma unroll
        for (int q = 0; q < 4; ++q){ rtv[wave][q] = bv[q]; rtc[wave][q] = bc[q]; }
        rlse[wave] = m + logf(s);
    }
    __syncthreads();
    __shared__ int spred[KBEAM];
    if (tid == 0){
        float gv[4] = {-INFINITY,-INFINITY,-INFINITY,-INFINITY};
        int gc[4] = {INT_MAX,INT_MAX,INT_MAX,INT_MAX};
        #pragma unroll
        for (int kl = 0; kl < KBEAM; ++kl){
            const int r2 = b*KBEAM + kl;
            float lse = rlse[kl];
            lse_all[t*BKR + r2] = lse;
            float off = ss[r2] - lse;
            if (off == -INFINITY){
                #pragma unroll
                for (int q = 0; q < 4; ++q) ins4(gv, gc, -INFINITY, kl*VOC + q);
            } else {
                #pragma unroll
                for (int q = 0; q < 4; ++q) ins4(gv, gc, rtv[kl][q] + off, kl*VOC + rtc[kl][q]);
            }
        }
        #pragma unroll
        for (int u = 0; u < KBEAM; ++u){
            int cand = gc[u]; float val = gv[u];
            int sym = cand % VOC; int pg = b*KBEAM + cand / VOC;
            int slot = b*KBEAM + u;
            scores_all[t*BKR + slot] = val;
            syms_all[t*BKR + slot] = sym;
            preds_all[t*BKR + slot] = pg;
            ss[slot] = (sym == EOS_TOK) ? -INFINITY : val;
            inp[slot] = sym;
            spred[u] = pg;
        }
    }
    __syncthreads();
    for (int x = tid; x < KBEAM*HD; x += 256){
        int u = x >> 9, j = x & 511;
        h_cur[(b*KBEAM+u)*HD + j] = h_new[spred[u]*HD + j];
    }
}

// ================= init =================
__global__ void init_kernel(const float* __restrict__ enc_h, float* __restrict__ h_cur,
    float* __restrict__ ss, int* __restrict__ inp)
{
    const int i = blockIdx.x;
    for (int j = threadIdx.x; j < HD; j += blockDim.x)
        h_cur[i*HD + j] = enc_h[(i & (BATCH-1))*HD + j];
    if (i == 0 && threadIdx.x < BKR){
        ss[threadIdx.x] = ((threadIdx.x & (KBEAM-1)) == 0) ? 0.f : -INFINITY;
        inp[threadIdx.x] = SOS_TOK;
    }
}

// ================= backtrack (single block, LDS-staged, parallel) =================
__global__ __launch_bounds__(256) void backtrack_kernel(
    const float* __restrict__ scores_all, const int* __restrict__ preds_all, const int* __restrict__ syms_all,
    const float* __restrict__ h_new_all, float* __restrict__ hn_fin,
    int* __restrict__ rmap, float* __restrict__ out)
{
    __shared__ int   l_syms[T_STEPS*BKR];     // 8 KB
    __shared__ int   l_preds[T_STEPS*BKR];    // 8 KB
    __shared__ float l_scores[T_STEPS*BKR];   // 8 KB
    __shared__ int   outrow_s[T_STEPS*BKR];   // 8 KB
    __shared__ int   cursym_s[T_STEPS*BKR];   // 8 KB
    __shared__ int tpred[64]; __shared__ float sfin[64]; __shared__ int lensq[64];
    __shared__ int eosf[BATCH];
    __shared__ int orow[64], csym[64], npred_s[64];
    __shared__ int cp_slot[64], cp_src[64]; __shared__ int nc_b[BATCH];
    __shared__ int reidx[64];
    const int tid = threadIdx.x;

    for (int x = tid; x < T_STEPS*BKR; x += 256){
        l_syms[x]   = syms_all[x];
        l_preds[x]  = preds_all[x];
        l_scores[x] = scores_all[x];
    }
    for (int x = tid; x < BKR*HD; x += 256) hn_fin[x] = 0.f;
    __syncthreads();

    if (tid < BATCH){
        const int b = tid;
        float v[KBEAM]; int used[KBEAM];
        #pragma unroll
        for (int k = 0; k < KBEAM; ++k){ v[k] = l_scores[(T_STEPS-1)*BKR + b*KBEAM + k]; used[k] = 0; }
        #pragma unroll
        for (int u = 0; u < KBEAM; ++u){
            int best = -1; float bvv = 0.f;
            #pragma unroll
            for (int k = 0; k < KBEAM; ++k) if (!used[k] && (best < 0 || v[k] > bvv)){ best = k; bvv = v[k]; }
            used[best] = 1;
            tpred[b*KBEAM+u] = b*KBEAM + best;
            sfin[b*KBEAM+u] = bvv;
            lensq[b*KBEAM+u] = T_STEPS;
        }
        eosf[b] = 0;
    }
    __syncthreads();

    for (int t = T_STEPS-1; t >= 0; --t){
        if (tid < 64){
            int tp = tpred[tid];
            orow[tid]   = tp;
            csym[tid]   = l_syms[t*BKR + tp];
            npred_s[tid]= l_preds[t*BKR + tp];
        }
        __syncthreads();
        if (tid < BATCH){
            const int b = tid;
            int eos[KBEAM]; int cnt = 0;
            #pragma unroll
            for (int k = 0; k < KBEAM; ++k) eos[k] = (l_syms[t*BKR + b*KBEAM + k] == EOS_TOK);
            int nc = 0;
            #pragma unroll
            for (int k = 0; k < KBEAM; ++k) if (eos[k]){
                int higher = 0;
                #pragma unroll
                for (int k2 = k+1; k2 < KBEAM; ++k2) higher += eos[k2];
                int occ = eosf[b] + higher;
                int rk = KBEAM - (occ % KBEAM) - 1;
                int slot = b*KBEAM + rk;
                int j = b*KBEAM + k;
                npred_s[slot] = l_preds[t*BKR + j];
                orow[slot]    = j;
                csym[slot]    = l_syms[t*BKR + j];
                sfin[slot]    = l_scores[t*BKR + j];
                lensq[slot]   = t + 1;
                cp_slot[b*KBEAM + nc] = slot;
                cp_src[b*KBEAM + nc]  = l_preds[t*BKR + j];
                ++nc; ++cnt;
            }
            nc_b[b] = nc;
            eosf[b] += cnt;
        }
        __syncthreads();
        if (tid < 64){
            outrow_s[t*BKR + tid] = orow[tid];
            cursym_s[t*BKR + tid] = csym[tid];
            tpred[tid] = npred_s[tid];
        }
        // hn_fin row copies: 4 threads per (b,q) entry
        {
            const int e = tid >> 2;           // 0..63 entry index
            const int eb = e >> 2, eq = e & 3;
            if (eq < nc_b[eb]){
                const int slot = cp_slot[eb*KBEAM + eq];
                const int src  = cp_src[eb*KBEAM + eq];
                const float4* sp = (const float4*)(h_new_all + (size_t)(t*BKR + src)*HD);
                float4* dp = (float4*)(hn_fin + (size_t)slot*HD);
                for (int j = (tid & 3); j < HD/4; j += 4) dp[j] = sp[j];
            }
        }
        __syncthreads();
    }

    if (tid < BATCH){
        const int b = tid;
        float v[KBEAM]; int used[KBEAM];
        #pragma unroll
        for (int k = 0; k < KBEAM; ++k){ v[k] = sfin[b*KBEAM+k]; used[k] = 0; }
        #pragma unroll
        for (int u = 0; u < KBEAM; ++u){
            int best = -1; float bvv = 0.f;
            #pragma unroll
            for (int k = 0; k < KBEAM; ++k) if (!used[k] && (best < 0 || v[k] > bvv)){ best = k; bvv = v[k]; }
            used[best] = 1;
            reidx[b*KBEAM+u] = best;
            out[O_SSRT + b*KBEAM + u] = bvv;
            out[O_LENS + b*KBEAM + u] = (float)lensq[b*KBEAM + best];
        }
    }
    __syncthreads();
    for (int x = tid; x < T_STEPS*BATCH; x += 256){
        int t2 = x >> 4, b = x & 15;
        rmap[x] = t2*BKR + outrow_s[t2*BKR + b*KBEAM + reidx[b*KBEAM]];
    }
    for (int x = tid; x < T_STEPS*BKR; x += 256){
        int t2 = x >> 6, rem = x & 63, b = rem >> 2, k = rem & 3;
        out[O_SEQS + x] = (float)cursym_s[t2*BKR + b*KBEAM + reidx[b*KBEAM + k]];
    }
    for (int x = tid; x < BATCH*HD; x += 256){
        int b = x >> 9, j = x & 511;
        out[O_HID + x] = hn_fin[(b*KBEAM + reidx[b*KBEAM])*HD + j];
    }
}

// ================= store-path output gather =================
__global__ void out_copy_kernel(const float* __restrict__ logits_all, const int* __restrict__ rmap,
    const float* __restrict__ lse_all, float* __restrict__ out)
{
    const int m = blockIdx.x;
    const int g = rmap[m];
    const float lse = lse_all[g];
    const float* src = logits_all + (size_t)g*VOC;
    float* dst = out + (size_t)m*VOC;
    for (int v = threadIdx.x; v < VOC; v += 256) dst[v] = src[v] - lse;
}

extern "C" void kernel_launch(void* const* d_in, const int* in_sizes, int n_in,
                              void* d_out, int out_size, void* d_ws, size_t ws_size,
                              hipStream_t stream)
{
    const float* enc_h = (const float*)d_in[0];
    const float* E     = (const float*)d_in[1];
    const float* W_ih  = (const float*)d_in[2];
    const float* W_hh  = (const float*)d_in[3];
    const float* b_ih  = (const float*)d_in[4];
    const float* b_hh  = (const float*)d_in[5];
    const float* Wo    = (const float*)d_in[6];
    const float* bo    = (const float*)d_in[7];
    float* out = (float*)d_out;

    float* w = (float*)d_ws;
    float* h_cur          = w + OFF_HCUR;
    float* gbuf           = w + OFF_GBUF;
    float* h_new_all      = w + OFF_HNEW;
    float* logits_scratch = w + OFF_LOGITS;
    float* lse_all        = w + OFF_LSE;
    float* ss             = w + OFF_SS;
    float* scores_all     = w + OFF_SCORES;
    float* hn_fin         = w + OFF_HNFIN;
    float* pv             = w + OFF_PV;
    float* pm             = w + OFF_PM;
    float* ps             = w + OFF_PS;
    int* wi        = (int*)(w + OFF_FEND);
    int* inp        = wi + IOFF_INP;
    int* preds_all  = wi + IOFF_PREDS;
    int* syms_all   = wi + IOFF_SYMS;
    int* rmap       = wi + IOFF_RMAP;
    int* pc         = wi + IOFF_PC;
    float* logits_all = w + OFF_LOGALL;

    const size_t need_store = (OFF_LOGALL + (size_t)T_STEPS*BKR*VOC) * sizeof(float);
    const bool store = (ws_size >= need_store);

    init_kernel<<<dim3(BKR), 256, 0, stream>>>(enc_h, h_cur, ss, inp);
    for (int t = 0; t < T_STEPS; ++t){
        float* logits_t = store ? (logits_all + (size_t)t*BKR*VOC) : logits_scratch;
        float* h_new_t  = h_new_all + (size_t)t*BKR*HD;
        gemm_gates_kernel<<<dim3(G3/64, 1, 2), 256, 0, stream>>>(E, inp, h_cur, W_ih, W_hh, b_ih, b_hh, gbuf);
        gru_combine_kernel<<<dim3(BKR*HD/256), 256, 0, stream>>>(gbuf, h_cur, h_new_t);
        gemm_logits_kernel<<<dim3(VOC/64), 256, 0, stream>>>(h_new_t, Wo, bo, logits_t);
        topk_phase_a<<<dim3(NSPLIT, BKR), 256, 0, stream>>>(logits_t, pv, pc, pm, ps);
        topk_phase_b<<<dim3(BATCH), 256, 0, stream>>>(pv, pc, pm, ps, t, scores_all, preds_all, syms_all,
                                                      ss, inp, lse_all, h_new_t, h_cur);
    }
    backtrack_kernel<<<dim3(1), 256, 0, stream>>>(scores_all, preds_all, syms_all, h_new_all, hn_fin,
                                                  rmap, out);
    if (store){
        out_copy_kernel<<<dim3(T_STEPS*BATCH), 256, 0, stream>>>(logits_all, rmap, lse_all, out);
    } else {
        gemm_final_kernel<<<dim3(VOC/64, T_STEPS*BATCH/64), 256, 0, stream>>>(h_new_all, rmap, lse_all, Wo, bo, out);
    }
}

// Round 4
// 2966.027 us; speedup vs baseline: 4.2769x; 1.1744x over previous
//
#include <hip/hip_runtime.h>
#include <math.h>
#include <limits.h>

#define T_STEPS 32
#define BATCH   16
#define KBEAM   4
#define BKR     64      // BATCH*KBEAM rows
#define HD      512
#define VOC     32000
#define G3      1536    // 3*HD
#define SOS_TOK 1
#define EOS_TOK 2
#define NSP     (VOC/64)      // 500 N-blocks of logits GEMM
#define NE      (NSP*4)       // 2000 top-4 partial entries per row

// ---- workspace layout (float offsets) ----
#define OFF_HCUR   ((size_t)0)
#define OFF_GBUF   (OFF_HCUR + (size_t)BKR*HD)
#define OFF_HNEW   (OFF_GBUF + (size_t)2*BKR*G3)
#define OFF_LSE    (OFF_HNEW + (size_t)T_STEPS*BKR*HD)
#define OFF_SS     (OFF_LSE + (size_t)T_STEPS*BKR)
#define OFF_SCORES (OFF_SS + BKR)
#define OFF_HNFIN  (OFF_SCORES + (size_t)T_STEPS*BKR)
#define OFF_PV     (OFF_HNFIN + (size_t)BKR*HD)            // [64][NSP][4]
#define OFF_PM     (OFF_PV + (size_t)BKR*NE)               // [64][NSP]
#define OFF_PS     (OFF_PM + (size_t)BKR*NSP)
#define OFF_FEND   (OFF_PS + (size_t)BKR*NSP)
// ---- int region (int offsets), base = (int*)(w + OFF_FEND) ----
#define IOFF_INP    0
#define IOFF_PREDS  64
#define IOFF_SYMS   (IOFF_PREDS + T_STEPS*BKR)
#define IOFF_RMAP   (IOFF_SYMS + T_STEPS*BKR)
#define IOFF_PC     (IOFF_RMAP + T_STEPS*BATCH)
#define IOFF_END    (IOFF_PC + BKR*NE)

// ---- output layout (float offsets into d_out) ----
#define O_HID  ((size_t)T_STEPS*BATCH*VOC)
#define O_SSRT (O_HID + (size_t)BATCH*HD)
#define O_LENS (O_SSRT + BATCH*KBEAM)
#define O_SEQS (O_LENS + BATCH*KBEAM)

typedef short bf16x8 __attribute__((ext_vector_type(8)));
typedef float f32x4  __attribute__((ext_vector_type(4)));

__device__ __forceinline__ unsigned short f2bf(float x){
    unsigned u = __float_as_uint(x);
    return (unsigned short)((u + 0x7fffu + ((u >> 16) & 1u)) >> 16);
}
__device__ __forceinline__ float bf2f(unsigned short h){
    return __uint_as_float(((unsigned)h) << 16);
}

// ============ MFMA split-bf16 GEMM core: C[64x64] = A[64x512] @ B[512 x 64(n0..)] ============
// A rows come from Abase + sidx[m]*HD (fp32). B is fp32 row-major with leading dim ldb.
// acc[g] = m-frag g (rows g*16..), this wave's n-subtile (cols wave*16..).
__device__ __forceinline__ void mfma_core(
    const float* __restrict__ Abase, const int* __restrict__ ridx, int mbase,
    const float* __restrict__ B, int ldb, int n0,
    unsigned short (&Ah)[64][40], unsigned short (&Al)[64][40],
    unsigned short (&Bh)[64][40], unsigned short (&Bl)[64][40],
    int (&sidx)[64], f32x4 (&acc)[4])
{
    const int tid = threadIdx.x;
    if (tid < 64) sidx[tid] = ridx ? ridx[mbase + tid] : (mbase + tid);
    #pragma unroll
    for (int g = 0; g < 4; ++g) acc[g] = (f32x4){0.f, 0.f, 0.f, 0.f};
    const int wave = tid >> 6, lane = tid & 63;
    const int am = tid >> 2, ak0 = (tid & 3) * 8;
    const int bn = tid & 63, br0 = (tid >> 6) * 8;
    __syncthreads();
    const float* bcol = B + n0 + bn;
    for (int kt = 0; kt < 16; ++kt){
        // --- stage A tile (64 rows x 32 k) as hi/lo bf16 ---
        {
            const float* ap = Abase + (size_t)sidx[am] * HD + kt * 32 + ak0;
            float4 x0 = *(const float4*)ap, x1 = *(const float4*)(ap + 4);
            float xs[8] = {x0.x, x0.y, x0.z, x0.w, x1.x, x1.y, x1.z, x1.w};
            union { unsigned short u[8]; uint4 v; } h8, l8;
            #pragma unroll
            for (int j = 0; j < 8; ++j){
                unsigned short h = f2bf(xs[j]);
                h8.u[j] = h; l8.u[j] = f2bf(xs[j] - bf2f(h));
            }
            *(uint4*)&Ah[am][ak0] = h8.v;
            *(uint4*)&Al[am][ak0] = l8.v;
        }
        // --- stage B tile (32 k x 64 n), transposed into [n][k] hi/lo ---
        {
            const float* bp = bcol + (size_t)(kt * 32 + br0) * ldb;
            union { unsigned short u[8]; uint4 v; } h8, l8;
            #pragma unroll
            for (int j = 0; j < 8; ++j){
                float x = bp[(size_t)j * ldb];
                unsigned short h = f2bf(x);
                h8.u[j] = h; l8.u[j] = f2bf(x - bf2f(h));
            }
            *(uint4*)&Bh[bn][br0] = h8.v;
            *(uint4*)&Bl[bn][br0] = l8.v;
        }
        __syncthreads();
        bf16x8 bh = *(const bf16x8*)&Bh[wave * 16 + (lane & 15)][(lane >> 4) * 8];
        bf16x8 bl = *(const bf16x8*)&Bl[wave * 16 + (lane & 15)][(lane >> 4) * 8];
        #pragma unroll
        for (int g = 0; g < 4; ++g){
            bf16x8 ah = *(const bf16x8*)&Ah[g * 16 + (lane & 15)][(lane >> 4) * 8];
            bf16x8 al = *(const bf16x8*)&Al[g * 16 + (lane & 15)][(lane >> 4) * 8];
            acc[g] = __builtin_amdgcn_mfma_f32_16x16x32_bf16(ah, bh, acc[g], 0, 0, 0);
            acc[g] = __builtin_amdgcn_mfma_f32_16x16x32_bf16(ah, bl, acc[g], 0, 0, 0);
            acc[g] = __builtin_amdgcn_mfma_f32_16x16x32_bf16(al, bh, acc[g], 0, 0, 0);
        }
        __syncthreads();
    }
}

__device__ __forceinline__ void dump_C(f32x4 (&acc)[4], float (&Cs)[64][65], int wave, int lane){
    #pragma unroll
    for (int g = 0; g < 4; ++g){
        int row = g * 16 + (lane >> 4) * 4;
        int col = wave * 16 + (lane & 15);
        #pragma unroll
        for (int r = 0; r < 4; ++r) Cs[row + r][col] = acc[g][r];
    }
}

// ================= gates GEMM (MFMA): gbuf[z] = A @ W + 0 (bias added in epilogue) ==========
__global__ __launch_bounds__(256) void gates_mfma_kernel(
    const float* __restrict__ E, const int* __restrict__ inp, const float* __restrict__ h_cur,
    const float* __restrict__ W_ih, const float* __restrict__ W_hh,
    const float* __restrict__ b_ih, const float* __restrict__ b_hh,
    float* __restrict__ gbuf)
{
    __shared__ unsigned short Ah[64][40], Al[64][40], Bh[64][40], Bl[64][40];
    __shared__ int sidx[64];
    __shared__ float Cs[64][65];
    const int z = blockIdx.y;
    const int n0 = blockIdx.x * 64;
    const int tid = threadIdx.x;
    f32x4 acc[4];
    mfma_core(z ? h_cur : E, z ? nullptr : inp, 0,
              z ? W_hh : W_ih, G3, n0, Ah, Al, Bh, Bl, sidx, acc);
    dump_C(acc, Cs, tid >> 6, tid & 63);
    __syncthreads();
    const float* bias = z ? b_hh : b_ih;
    const int row = tid >> 2, c0 = (tid & 3) * 16;
    float* gp = gbuf + (size_t)z * BKR * G3 + (size_t)row * G3 + n0 + c0;
    #pragma unroll
    for (int q = 0; q < 4; ++q){
        float4 bz = *(const float4*)(bias + n0 + c0 + q * 4);
        float4 v;
        v.x = Cs[row][c0 + q*4 + 0] + bz.x;
        v.y = Cs[row][c0 + q*4 + 1] + bz.y;
        v.z = Cs[row][c0 + q*4 + 2] + bz.z;
        v.w = Cs[row][c0 + q*4 + 3] + bz.w;
        *(float4*)(gp + q * 4) = v;
    }
}

// ================= GRU combine =================
__global__ void gru_combine_kernel(const float* __restrict__ gbuf, const float* __restrict__ h_cur,
    float* __restrict__ h_new)
{
    int x = blockIdx.x * 256 + threadIdx.x;
    int i = x >> 9, j = x & 511;
    const float* gi = gbuf + (size_t)i * G3;
    const float* gh = gbuf + (size_t)BKR * G3 + (size_t)i * G3;
    float ir = gi[j], iz = gi[j + 512], inn = gi[j + 1024];
    float hr = gh[j], hz = gh[j + 512], hnv = gh[j + 1024];
    float r  = 1.f / (1.f + expf(-(ir + hr)));
    float zz = 1.f / (1.f + expf(-(iz + hz)));
    float n  = tanhf(inn + r * hnv);
    h_new[x] = (1.f - zz) * n + zz * h_cur[x];
}

// ============ top-4 insertion with JAX tie semantics (val desc, cand asc) ============
__device__ __forceinline__ void ins4(float* bv, int* bc, float s, int c){
    bool g0 = (s > bv[0]) || (s == bv[0] && c < bc[0]);
    bool g1 = (s > bv[1]) || (s == bv[1] && c < bc[1]);
    bool g2 = (s > bv[2]) || (s == bv[2] && c < bc[2]);
    bool g3 = (s > bv[3]) || (s == bv[3] && c < bc[3]);
    if (g0){ bv[3]=bv[2];bc[3]=bc[2]; bv[2]=bv[1];bc[2]=bc[1]; bv[1]=bv[0];bc[1]=bc[0]; bv[0]=s; bc[0]=c; }
    else if (g1){ bv[3]=bv[2];bc[3]=bc[2]; bv[2]=bv[1];bc[2]=bc[1]; bv[1]=s; bc[1]=c; }
    else if (g2){ bv[3]=bv[2];bc[3]=bc[2]; bv[2]=s; bc[2]=c; }
    else if (g3){ bv[3]=s; bc[3]=c; }
}

// ========== logits GEMM + fused per-block top-4/lse partials (logits never hit memory) =======
__global__ __launch_bounds__(256) void logits_topk_kernel(const float* __restrict__ h_new,
    const float* __restrict__ Wo, const float* __restrict__ bo,
    float* __restrict__ pv, int* __restrict__ pc, float* __restrict__ pm, float* __restrict__ ps)
{
    __shared__ unsigned short Ah[64][40], Al[64][40], Bh[64][40], Bl[64][40];
    __shared__ int sidx[64];
    __shared__ float Cs[64][65];
    const int bx = blockIdx.x, n0 = bx * 64;
    const int tid = threadIdx.x;
    f32x4 acc[4];
    mfma_core(h_new, nullptr, 0, Wo, VOC, n0, Ah, Al, Bh, Bl, sidx, acc);
    dump_C(acc, Cs, tid >> 6, tid & 63);
    __syncthreads();
    // per-row scan: threads 4r..4r+3 share row r, 16 cols each
    const int row = tid >> 2, c0 = (tid & 3) * 16;
    float bv[4] = {-INFINITY,-INFINITY,-INFINITY,-INFINITY};
    int bc[4] = {INT_MAX, INT_MAX, INT_MAX, INT_MAX};
    float m = -INFINITY, s = 0.f;
    #pragma unroll
    for (int j = 0; j < 16; ++j){
        float x = Cs[row][c0 + j] + bo[n0 + c0 + j];
        if (x > m){ s = s * expf(m - x) + 1.f; m = x; }
        else s += expf(x - m);
        ins4(bv, bc, x, n0 + c0 + j);
    }
    // merge the 4 threads of this row (lanes differ in bits 0..1 -> same wave)
    #pragma unroll
    for (int o = 1; o < 4; o <<= 1){
        float ov[4]; int oc[4];
        #pragma unroll
        for (int q = 0; q < 4; ++q){ ov[q] = __shfl_xor(bv[q], o); oc[q] = __shfl_xor(bc[q], o); }
        #pragma unroll
        for (int q = 0; q < 4; ++q) ins4(bv, bc, ov[q], oc[q]);
        float m2 = __shfl_xor(m, o), s2 = __shfl_xor(s, o);
        float M = fmaxf(m, m2);
        s = s * expf(m - M) + s2 * expf(m2 - M);
        m = M;
    }
    if ((tid & 3) == 0){
        const size_t base = (size_t)row * NE + (size_t)bx * 4;
        #pragma unroll
        for (int q = 0; q < 4; ++q){ pv[base + q] = bv[q]; pc[base + q] = bc[q]; }
        pm[row * NSP + bx] = m; ps[row * NSP + bx] = s;
    }
}

// ========== final re-computation GEMM: out = A[rmap] @ Wo + bo - lse[rmap] ==========
__global__ __launch_bounds__(256) void final_mfma_kernel(const float* __restrict__ h_new_all,
    const int* __restrict__ rmap, const float* __restrict__ lse_all,
    const float* __restrict__ Wo, const float* __restrict__ bo, float* __restrict__ out)
{
    __shared__ unsigned short Ah[64][40], Al[64][40], Bh[64][40], Bl[64][40];
    __shared__ int sidx[64];
    __shared__ float Cs[64][65];
    __shared__ float subm[64];
    const int n0 = blockIdx.x * 64, mb = blockIdx.y * 64;
    const int tid = threadIdx.x;
    f32x4 acc[4];
    mfma_core(h_new_all, rmap, mb, Wo, VOC, n0, Ah, Al, Bh, Bl, sidx, acc);
    dump_C(acc, Cs, tid >> 6, tid & 63);
    if (tid < 64) subm[tid] = lse_all[sidx[tid]];
    __syncthreads();
    const int row = tid >> 2, c0 = (tid & 3) * 16;
    const float sub = subm[row];
    float* op = out + (size_t)(mb + row) * VOC + n0 + c0;
    #pragma unroll
    for (int q = 0; q < 4; ++q){
        float4 bz = *(const float4*)(bo + n0 + c0 + q * 4);
        float4 v;
        v.x = Cs[row][c0 + q*4 + 0] + bz.x - sub;
        v.y = Cs[row][c0 + q*4 + 1] + bz.y - sub;
        v.z = Cs[row][c0 + q*4 + 2] + bz.z - sub;
        v.w = Cs[row][c0 + q*4 + 3] + bz.w - sub;
        *(float4*)(op + q * 4) = v;
    }
}

// ========== phase B: merge NSP partials/row, apply ss-lse, batch top-4, advance state ========
__global__ __launch_bounds__(256) void topk_phase_b(
    const float* __restrict__ pv, const int* __restrict__ pc,
    const float* __restrict__ pm, const float* __restrict__ ps,
    int t,
    float* __restrict__ scores_all, int* __restrict__ preds_all, int* __restrict__ syms_all,
    float* __restrict__ ss, int* __restrict__ inp, float* __restrict__ lse_all,
    const float* __restrict__ h_new, float* __restrict__ h_cur)
{
    const int b = blockIdx.x, tid = threadIdx.x;
    const int wave = tid >> 6, lane = tid & 63;
    const int row = b * KBEAM + wave;            // wave w handles beam-row w

    // --- per-row top-4 merge over NE entries (coalesced: consecutive lanes, consecutive e) ---
    float bv[4] = {-INFINITY,-INFINITY,-INFINITY,-INFINITY};
    int bc[4] = {INT_MAX, INT_MAX, INT_MAX, INT_MAX};
    for (int e = lane; e < NE; e += 64)
        ins4(bv, bc, pv[(size_t)row * NE + e], pc[(size_t)row * NE + e]);
    #pragma unroll
    for (int o = 1; o < 64; o <<= 1){
        float ov[4]; int oc[4];
        #pragma unroll
        for (int q = 0; q < 4; ++q){ ov[q] = __shfl_xor(bv[q], o); oc[q] = __shfl_xor(bc[q], o); }
        #pragma unroll
        for (int q = 0; q < 4; ++q) ins4(bv, bc, ov[q], oc[q]);
    }
    // --- lse merge over NSP partials (every lane has >=7 entries -> finite before butterfly) ---
    float m = -INFINITY, s = 0.f;
    for (int e = lane; e < NSP; e += 64){
        float m2 = pm[row * NSP + e], s2 = ps[row * NSP + e];
        float M = fmaxf(m, m2);
        s = s * expf(m - M) + s2 * expf(m2 - M);
        m = M;
    }
    #pragma unroll
    for (int o = 1; o < 64; o <<= 1){
        float m2 = __shfl_xor(m, o), s2 = __shfl_xor(s, o);
        float M = fmaxf(m, m2);
        s = s * expf(m - M) + s2 * expf(m2 - M);
        m = M;
    }
    __shared__ float rtv[KBEAM][4]; __shared__ int rtc[KBEAM][4];
    __shared__ float rlse[KBEAM];
    if (lane == 0){
        #pragma unroll
        for (int q = 0; q < 4; ++q){ rtv[wave][q] = bv[q]; rtc[wave][q] = bc[q]; }
        rlse[wave] = m + logf(s);
    }
    __syncthreads();
    __shared__ int spred[KBEAM];
    if (tid == 0){
        float gv[4] = {-INFINITY,-INFINITY,-INFINITY,-INFINITY};
        int gc[4] = {INT_MAX, INT_MAX, INT_MAX, INT_MAX};
        #pragma unroll
        for (int kl = 0; kl < KBEAM; ++kl){
            const int r2 = b * KBEAM + kl;
            float lse = rlse[kl];
            lse_all[t * BKR + r2] = lse;
            float off = ss[r2] - lse;
            if (off == -INFINITY){
                #pragma unroll
                for (int q = 0; q < 4; ++q) ins4(gv, gc, -INFINITY, kl * VOC + q);
            } else {
                #pragma unroll
                for (int q = 0; q < 4; ++q) ins4(gv, gc, rtv[kl][q] + off, kl * VOC + rtc[kl][q]);
            }
        }
        #pragma unroll
        for (int u = 0; u < KBEAM; ++u){
            int cand = gc[u]; float val = gv[u];
            int sym = cand % VOC; int pg = b * KBEAM + cand / VOC;
            int slot = b * KBEAM + u;
            scores_all[t * BKR + slot] = val;
            syms_all[t * BKR + slot] = sym;
            preds_all[t * BKR + slot] = pg;
            ss[slot] = (sym == EOS_TOK) ? -INFINITY : val;
            inp[slot] = sym;
            spred[u] = pg;
        }
    }
    __syncthreads();
    for (int x = tid; x < KBEAM * HD; x += 256){
        int u = x >> 9, j = x & 511;
        h_cur[(b * KBEAM + u) * HD + j] = h_new[spred[u] * HD + j];
    }
}

// ================= init =================
__global__ void init_kernel(const float* __restrict__ enc_h, float* __restrict__ h_cur,
    float* __restrict__ ss, int* __restrict__ inp)
{
    const int i = blockIdx.x;
    for (int j = threadIdx.x; j < HD; j += blockDim.x)
        h_cur[i * HD + j] = enc_h[(i & (BATCH - 1)) * HD + j];
    if (i == 0 && threadIdx.x < BKR){
        ss[threadIdx.x] = ((threadIdx.x & (KBEAM - 1)) == 0) ? 0.f : -INFINITY;
        inp[threadIdx.x] = SOS_TOK;
    }
}

// ================= backtrack (single block, LDS-staged, parallel) =================
__global__ __launch_bounds__(256) void backtrack_kernel(
    const float* __restrict__ scores_all, const int* __restrict__ preds_all, const int* __restrict__ syms_all,
    const float* __restrict__ h_new_all, float* __restrict__ hn_fin,
    int* __restrict__ rmap, float* __restrict__ out)
{
    __shared__ int   l_syms[T_STEPS*BKR];
    __shared__ int   l_preds[T_STEPS*BKR];
    __shared__ float l_scores[T_STEPS*BKR];
    __shared__ int   outrow_s[T_STEPS*BKR];
    __shared__ int   cursym_s[T_STEPS*BKR];
    __shared__ int tpred[64]; __shared__ float sfin[64]; __shared__ int lensq[64];
    __shared__ int eosf[BATCH];
    __shared__ int orow[64], csym[64], npred_s[64];
    __shared__ int cp_slot[64], cp_src[64]; __shared__ int nc_b[BATCH];
    __shared__ int reidx[64];
    const int tid = threadIdx.x;

    for (int x = tid; x < T_STEPS*BKR; x += 256){
        l_syms[x]   = syms_all[x];
        l_preds[x]  = preds_all[x];
        l_scores[x] = scores_all[x];
    }
    for (int x = tid; x < BKR*HD; x += 256) hn_fin[x] = 0.f;
    __syncthreads();

    if (tid < BATCH){
        const int b = tid;
        float v[KBEAM]; int used[KBEAM];
        #pragma unroll
        for (int k = 0; k < KBEAM; ++k){ v[k] = l_scores[(T_STEPS-1)*BKR + b*KBEAM + k]; used[k] = 0; }
        #pragma unroll
        for (int u = 0; u < KBEAM; ++u){
            int best = -1; float bvv = 0.f;
            #pragma unroll
            for (int k = 0; k < KBEAM; ++k) if (!used[k] && (best < 0 || v[k] > bvv)){ best = k; bvv = v[k]; }
            used[best] = 1;
            tpred[b*KBEAM+u] = b*KBEAM + best;
            sfin[b*KBEAM+u] = bvv;
            lensq[b*KBEAM+u] = T_STEPS;
        }
        eosf[b] = 0;
    }
    __syncthreads();

    for (int t = T_STEPS-1; t >= 0; --t){
        if (tid < 64){
            int tp = tpred[tid];
            orow[tid]    = tp;
            csym[tid]    = l_syms[t*BKR + tp];
            npred_s[tid] = l_preds[t*BKR + tp];
        }
        __syncthreads();
        if (tid < BATCH){
            const int b = tid;
            int eos[KBEAM]; int cnt = 0;
            #pragma unroll
            for (int k = 0; k < KBEAM; ++k) eos[k] = (l_syms[t*BKR + b*KBEAM + k] == EOS_TOK);
            int nc = 0;
            #pragma unroll
            for (int k = 0; k < KBEAM; ++k) if (eos[k]){
                int higher = 0;
                #pragma unroll
                for (int k2 = k+1; k2 < KBEAM; ++k2) higher += eos[k2];
                int occ = eosf[b] + higher;
                int rk = KBEAM - (occ % KBEAM) - 1;
                int slot = b*KBEAM + rk;
                int j = b*KBEAM + k;
                npred_s[slot] = l_preds[t*BKR + j];
                orow[slot]    = j;
                csym[slot]    = l_syms[t*BKR + j];
                sfin[slot]    = l_scores[t*BKR + j];
                lensq[slot]   = t + 1;
                cp_slot[b*KBEAM + nc] = slot;
                cp_src[b*KBEAM + nc]  = l_preds[t*BKR + j];
                ++nc; ++cnt;
            }
            nc_b[b] = nc;
            eosf[b] += cnt;
        }
        __syncthreads();
        if (tid < 64){
            outrow_s[t*BKR + tid] = orow[tid];
            cursym_s[t*BKR + tid] = csym[tid];
            tpred[tid] = npred_s[tid];
        }
        {
            const int e = tid >> 2;
            const int eb = e >> 2, eq = e & 3;
            if (eq < nc_b[eb]){
                const int slot = cp_slot[eb*KBEAM + eq];
                const int src  = cp_src[eb*KBEAM + eq];
                const float4* sp = (const float4*)(h_new_all + (size_t)(t*BKR + src)*HD);
                float4* dp = (float4*)(hn_fin + (size_t)slot*HD);
                for (int j = (tid & 3); j < HD/4; j += 4) dp[j] = sp[j];
            }
        }
        __syncthreads();
    }

    if (tid < BATCH){
        const int b = tid;
        float v[KBEAM]; int used[KBEAM];
        #pragma unroll
        for (int k = 0; k < KBEAM; ++k){ v[k] = sfin[b*KBEAM+k]; used[k] = 0; }
        #pragma unroll
        for (int u = 0; u < KBEAM; ++u){
            int best = -1; float bvv = 0.f;
            #pragma unroll
            for (int k = 0; k < KBEAM; ++k) if (!used[k] && (best < 0 || v[k] > bvv)){ best = k; bvv = v[k]; }
            used[best] = 1;
            reidx[b*KBEAM+u] = best;
            out[O_SSRT + b*KBEAM + u] = bvv;
            out[O_LENS + b*KBEAM + u] = (float)lensq[b*KBEAM + best];
        }
    }
    __syncthreads();
    for (int x = tid; x < T_STEPS*BATCH; x += 256){
        int t2 = x >> 4, b = x & 15;
        rmap[x] = t2*BKR + outrow_s[t2*BKR + b*KBEAM + reidx[b*KBEAM]];
    }
    for (int x = tid; x < T_STEPS*BKR; x += 256){
        int t2 = x >> 6, rem = x & 63, b = rem >> 2, k = rem & 3;
        out[O_SEQS + x] = (float)cursym_s[t2*BKR + b*KBEAM + reidx[b*KBEAM + k]];
    }
    for (int x = tid; x < BATCH*HD; x += 256){
        int b = x >> 9, j = x & 511;
        out[O_HID + x] = hn_fin[(b*KBEAM + reidx[b*KBEAM])*HD + j];
    }
}

extern "C" void kernel_launch(void* const* d_in, const int* in_sizes, int n_in,
                              void* d_out, int out_size, void* d_ws, size_t ws_size,
                              hipStream_t stream)
{
    const float* enc_h = (const float*)d_in[0];
    const float* E     = (const float*)d_in[1];
    const float* W_ih  = (const float*)d_in[2];
    const float* W_hh  = (const float*)d_in[3];
    const float* b_ih  = (const float*)d_in[4];
    const float* b_hh  = (const float*)d_in[5];
    const float* Wo    = (const float*)d_in[6];
    const float* bo    = (const float*)d_in[7];
    float* out = (float*)d_out;

    float* w = (float*)d_ws;
    float* h_cur      = w + OFF_HCUR;
    float* gbuf       = w + OFF_GBUF;
    float* h_new_all  = w + OFF_HNEW;
    float* lse_all    = w + OFF_LSE;
    float* ss         = w + OFF_SS;
    float* scores_all = w + OFF_SCORES;
    float* hn_fin     = w + OFF_HNFIN;
    float* pv         = w + OFF_PV;
    float* pm         = w + OFF_PM;
    float* ps         = w + OFF_PS;
    int* wi         = (int*)(w + OFF_FEND);
    int* inp        = wi + IOFF_INP;
    int* preds_all  = wi + IOFF_PREDS;
    int* syms_all   = wi + IOFF_SYMS;
    int* rmap       = wi + IOFF_RMAP;
    int* pc         = wi + IOFF_PC;

    init_kernel<<<dim3(BKR), 256, 0, stream>>>(enc_h, h_cur, ss, inp);
    for (int t = 0; t < T_STEPS; ++t){
        float* h_new_t = h_new_all + (size_t)t * BKR * HD;
        gates_mfma_kernel<<<dim3(G3/64, 2), 256, 0, stream>>>(E, inp, h_cur, W_ih, W_hh, b_ih, b_hh, gbuf);
        gru_combine_kernel<<<dim3(BKR*HD/256), 256, 0, stream>>>(gbuf, h_cur, h_new_t);
        logits_topk_kernel<<<dim3(NSP), 256, 0, stream>>>(h_new_t, Wo, bo, pv, pc, pm, ps);
        topk_phase_b<<<dim3(BATCH), 256, 0, stream>>>(pv, pc, pm, ps, t, scores_all, preds_all, syms_all,
                                                      ss, inp, lse_all, h_new_t, h_cur);
    }
    backtrack_kernel<<<dim3(1), 256, 0, stream>>>(scores_all, preds_all, syms_all, h_new_all, hn_fin,
                                                  rmap, out);
    final_mfma_kernel<<<dim3(NSP, T_STEPS*BATCH/64), 256, 0, stream>>>(h_new_all, rmap, lse_all, Wo, bo, out);
}

// Round 5
// 2787.014 us; speedup vs baseline: 4.5516x; 1.0642x over previous
//
#include <hip/hip_runtime.h>
#include <math.h>
#include <limits.h>

#define T_STEPS 32
#define BATCH   16
#define KBEAM   4
#define BKR     64      // BATCH*KBEAM rows
#define HD      512
#define VOC     32000
#define G3      1536    // 3*HD
#define SOS_TOK 1
#define EOS_TOK 2
#define NSP     (VOC/64)      // 500 N-blocks of logits GEMM
#define NE      (NSP*4)       // 2000 top-4 partial entries per row
#define NBG     (G3/64)       // 24 N-blocks of gates GEMM
#define FMBL    4             // m-blocks looped per final block

// ---- workspace layout (float offsets) ----
#define OFF_HCUR   ((size_t)0)
#define OFF_GBUF   (OFF_HCUR + (size_t)BKR*HD)
#define OFF_HNEW   (OFF_GBUF + (size_t)2*BKR*G3)
#define OFF_LSE    (OFF_HNEW + (size_t)T_STEPS*BKR*HD)
#define OFF_SS     (OFF_LSE + (size_t)T_STEPS*BKR)
#define OFF_SCORES (OFF_SS + BKR)
#define OFF_HNFIN  (OFF_SCORES + (size_t)T_STEPS*BKR)
#define OFF_PV     (OFF_HNFIN + (size_t)BKR*HD)            // [64][NE]
#define OFF_PM     (OFF_PV + (size_t)BKR*NE)               // [64][NSP]
#define OFF_PS     (OFF_PM + (size_t)BKR*NSP)
#define OFF_FEND   (OFF_PS + (size_t)BKR*NSP)
// ---- int region (int offsets), base = (int*)(w + OFF_FEND) ----
#define IOFF_INP    0
#define IOFF_PREDS  64
#define IOFF_SYMS   (IOFF_PREDS + T_STEPS*BKR)
#define IOFF_RMAP   (IOFF_SYMS + T_STEPS*BKR)
#define IOFF_PC     (IOFF_RMAP + T_STEPS*BATCH)
#define IOFF_END    (IOFF_PC + BKR*NE)
// ---- short region (short offsets), base = (unsigned short*)(wi + IOFF_END) ----
#define S_WOH   ((size_t)0)                        // [NSP][16][2048]
#define S_WOL   (S_WOH + (size_t)NSP*16*2048)      // 16384000
#define S_WGH   (S_WOL + (size_t)NSP*16*2048)      // [2][NBG][16][2048]
#define S_WGL   (S_WGH + (size_t)2*NBG*16*2048)
#define S_HNH   (S_WGL + (size_t)2*NBG*16*2048)    // [T][64][512]
#define S_HNL   (S_HNH + (size_t)T_STEPS*BKR*HD)
#define S_HCH   (S_HNL + (size_t)T_STEPS*BKR*HD)   // [64][512]
#define S_HCL   (S_HCH + (size_t)BKR*HD)
#define S_EIH   (S_HCL + (size_t)BKR*HD)
#define S_EIL   (S_EIH + (size_t)BKR*HD)
#define S_END   (S_EIL + (size_t)BKR*HD)

// ---- output layout (float offsets into d_out) ----
#define O_HID  ((size_t)T_STEPS*BATCH*VOC)
#define O_SSRT (O_HID + (size_t)BATCH*HD)
#define O_LENS (O_SSRT + BATCH*KBEAM)
#define O_SEQS (O_LENS + BATCH*KBEAM)

typedef short bf16x8 __attribute__((ext_vector_type(8)));
typedef float f32x4  __attribute__((ext_vector_type(4)));

__device__ __forceinline__ unsigned short f2bf(float x){
    unsigned u = __float_as_uint(x);
    return (unsigned short)((u + 0x7fffu + ((u >> 16) & 1u)) >> 16);
}
__device__ __forceinline__ float bf2f(unsigned short h){
    return __uint_as_float(((unsigned)h) << 16);
}

__device__ __forceinline__ void dump_C(f32x4 (&acc)[4], float (&Cs)[64][65], int wave, int lane){
    #pragma unroll
    for (int g = 0; g < 4; ++g){
        int row = g * 16 + (lane >> 4) * 4;
        int col = wave * 16 + (lane & 15);
        #pragma unroll
        for (int r = 0; r < 4; ++r) Cs[row + r][col] = acc[g][r];
    }
}

// ============ top-4 insertion with JAX tie semantics (val desc, cand asc) ============
__device__ __forceinline__ void ins4(float* bv, int* bc, float s, int c){
    bool g0 = (s > bv[0]) || (s == bv[0] && c < bc[0]);
    bool g1 = (s > bv[1]) || (s == bv[1] && c < bc[1]);
    bool g2 = (s > bv[2]) || (s == bv[2] && c < bc[2]);
    bool g3 = (s > bv[3]) || (s == bv[3] && c < bc[3]);
    if (g0){ bv[3]=bv[2];bc[3]=bc[2]; bv[2]=bv[1];bc[2]=bc[1]; bv[1]=bv[0];bc[1]=bc[0]; bv[0]=s; bc[0]=c; }
    else if (g1){ bv[3]=bv[2];bc[3]=bc[2]; bv[2]=bv[1];bc[2]=bc[1]; bv[1]=s; bc[1]=c; }
    else if (g2){ bv[3]=bv[2];bc[3]=bc[2]; bv[2]=s; bc[2]=c; }
    else if (g3){ bv[3]=s; bc[3]=c; }
}

// =================================================================================
// ============================ PREPACKED (fast) path ==============================
// =================================================================================

// W (fp32, HD x N row-major) -> tiles [N/64][16][64n x 32k] hi/lo bf16
__global__ __launch_bounds__(256) void prepack_kernel(const float* __restrict__ W, int N,
    unsigned short* __restrict__ oh, unsigned short* __restrict__ ol)
{
    const int bx = blockIdx.x, kt = blockIdx.y, tid = threadIdx.x;
    const int bn = tid >> 2, kq = (tid & 3) * 8;
    union { unsigned short u[8]; uint4 v; } h8, l8;
    #pragma unroll
    for (int j = 0; j < 8; ++j){
        float x = W[(size_t)(kt*32 + kq + j) * (size_t)N + bx*64 + bn];
        unsigned short h = f2bf(x);
        h8.u[j] = h; l8.u[j] = f2bf(x - bf2f(h));
    }
    const size_t base = ((size_t)bx*16 + kt) * 2048 + (size_t)tid * 8;
    *(uint4*)(oh + base) = h8.v;
    *(uint4*)(ol + base) = l8.v;
}

// core kt-loop, pre-split A[64][512] (rows direct) and B tile base [16][2048]
__device__ __forceinline__ void mfma_core_pre(
    const unsigned short* __restrict__ ahg, const unsigned short* __restrict__ alg,
    const unsigned short* __restrict__ bth, const unsigned short* __restrict__ btl,
    unsigned short (&Ah)[64][40], unsigned short (&Al)[64][40],
    unsigned short (&Bh)[64][40], unsigned short (&Bl)[64][40],
    f32x4 (&acc)[4])
{
    const int tid = threadIdx.x;
    const int row = tid >> 2, kq = (tid & 3) * 8;
    const int wave = tid >> 6, lane = tid & 63;
    #pragma unroll
    for (int g = 0; g < 4; ++g) acc[g] = (f32x4){0.f, 0.f, 0.f, 0.f};
    for (int kt = 0; kt < 16; ++kt){
        *(uint4*)&Ah[row][kq] = *(const uint4*)(ahg + (size_t)row*512 + kt*32 + kq);
        *(uint4*)&Al[row][kq] = *(const uint4*)(alg + (size_t)row*512 + kt*32 + kq);
        *(uint4*)&Bh[row][kq] = *(const uint4*)(bth + (size_t)kt*2048 + (size_t)tid*8);
        *(uint4*)&Bl[row][kq] = *(const uint4*)(btl + (size_t)kt*2048 + (size_t)tid*8);
        __syncthreads();
        bf16x8 bh = *(const bf16x8*)&Bh[wave*16 + (lane&15)][(lane>>4)*8];
        bf16x8 bl = *(const bf16x8*)&Bl[wave*16 + (lane&15)][(lane>>4)*8];
        #pragma unroll
        for (int g = 0; g < 4; ++g){
            bf16x8 ah = *(const bf16x8*)&Ah[g*16 + (lane&15)][(lane>>4)*8];
            bf16x8 al = *(const bf16x8*)&Al[g*16 + (lane&15)][(lane>>4)*8];
            acc[g] = __builtin_amdgcn_mfma_f32_16x16x32_bf16(ah, bh, acc[g], 0, 0, 0);
            acc[g] = __builtin_amdgcn_mfma_f32_16x16x32_bf16(ah, bl, acc[g], 0, 0, 0);
            acc[g] = __builtin_amdgcn_mfma_f32_16x16x32_bf16(al, bh, acc[g], 0, 0, 0);
        }
        __syncthreads();
    }
}

__global__ __launch_bounds__(256) void gates_pre_kernel(
    const unsigned short* __restrict__ eih, const unsigned short* __restrict__ eil,
    const unsigned short* __restrict__ hch, const unsigned short* __restrict__ hcl,
    const unsigned short* __restrict__ wgh, const unsigned short* __restrict__ wgl,
    const float* __restrict__ b_ih, const float* __restrict__ b_hh,
    float* __restrict__ gbuf)
{
    __shared__ unsigned short Ah[64][40], Al[64][40], Bh[64][40], Bl[64][40];
    __shared__ float Cs[64][65];
    const int z = blockIdx.y, bx = blockIdx.x, n0 = bx * 64;
    const int tid = threadIdx.x;
    const unsigned short* ahg = z ? hch : eih;
    const unsigned short* alg = z ? hcl : eil;
    const size_t bt = ((size_t)z*NBG + bx) * 16 * 2048;
    f32x4 acc[4];
    mfma_core_pre(ahg, alg, wgh + bt, wgl + bt, Ah, Al, Bh, Bl, acc);
    dump_C(acc, Cs, tid >> 6, tid & 63);
    __syncthreads();
    const float* bias = z ? b_hh : b_ih;
    const int row = tid >> 2, c0 = (tid & 3) * 16;
    float* gp = gbuf + (size_t)z * BKR * G3 + (size_t)row * G3 + n0 + c0;
    #pragma unroll
    for (int q = 0; q < 4; ++q){
        float4 bz = *(const float4*)(bias + n0 + c0 + q * 4);
        float4 v;
        v.x = Cs[row][c0 + q*4 + 0] + bz.x;
        v.y = Cs[row][c0 + q*4 + 1] + bz.y;
        v.z = Cs[row][c0 + q*4 + 2] + bz.z;
        v.w = Cs[row][c0 + q*4 + 3] + bz.w;
        *(float4*)(gp + q * 4) = v;
    }
}

__global__ __launch_bounds__(256) void logits_pre_kernel(
    const unsigned short* __restrict__ hnh, const unsigned short* __restrict__ hnl,
    const unsigned short* __restrict__ woh, const unsigned short* __restrict__ wol,
    const float* __restrict__ bo,
    float* __restrict__ pv, int* __restrict__ pc, float* __restrict__ pm, float* __restrict__ ps)
{
    __shared__ unsigned short Ah[64][40], Al[64][40], Bh[64][40], Bl[64][40];
    __shared__ float Cs[64][65];
    const int bx = blockIdx.x, n0 = bx * 64;
    const int tid = threadIdx.x;
    const size_t bt = (size_t)bx * 16 * 2048;
    f32x4 acc[4];
    mfma_core_pre(hnh, hnl, woh + bt, wol + bt, Ah, Al, Bh, Bl, acc);
    dump_C(acc, Cs, tid >> 6, tid & 63);
    __syncthreads();
    const int row = tid >> 2, c0 = (tid & 3) * 16;
    float bv[4] = {-INFINITY,-INFINITY,-INFINITY,-INFINITY};
    int bc[4] = {INT_MAX, INT_MAX, INT_MAX, INT_MAX};
    float m = -INFINITY, s = 0.f;
    #pragma unroll
    for (int j = 0; j < 16; ++j){
        float x = Cs[row][c0 + j] + bo[n0 + c0 + j];
        if (x > m){ s = s * expf(m - x) + 1.f; m = x; }
        else s += expf(x - m);
        ins4(bv, bc, x, n0 + c0 + j);
    }
    #pragma unroll
    for (int o = 1; o < 4; o <<= 1){
        float ov[4]; int oc[4];
        #pragma unroll
        for (int q = 0; q < 4; ++q){ ov[q] = __shfl_xor(bv[q], o); oc[q] = __shfl_xor(bc[q], o); }
        #pragma unroll
        for (int q = 0; q < 4; ++q) ins4(bv, bc, ov[q], oc[q]);
        float m2 = __shfl_xor(m, o), s2 = __shfl_xor(s, o);
        float M = fmaxf(m, m2);
        s = s * expf(m - M) + s2 * expf(m2 - M);
        m = M;
    }
    if ((tid & 3) == 0){
        const size_t base = (size_t)row * NE + (size_t)bx * 4;
        #pragma unroll
        for (int q = 0; q < 4; ++q){ pv[base + q] = bv[q]; pc[base + q] = bc[q]; }
        pm[row * NSP + bx] = m; ps[row * NSP + bx] = s;
    }
}

__global__ __launch_bounds__(256) void final_pre_kernel(
    const unsigned short* __restrict__ hnh, const unsigned short* __restrict__ hnl,
    const int* __restrict__ rmap, const float* __restrict__ lse_all,
    const unsigned short* __restrict__ woh, const unsigned short* __restrict__ wol,
    const float* __restrict__ bo, float* __restrict__ out)
{
    __shared__ unsigned short Ah[64][40], Al[64][40], Bh[64][40], Bl[64][40];
    __shared__ float Cs[64][65];
    __shared__ int sidx[256]; __shared__ float subm[256];
    const int tid = threadIdx.x;
    const int bx = blockIdx.x, n0 = bx * 64;
    const int mbase = blockIdx.y * (64 * FMBL);
    sidx[tid] = rmap[mbase + tid];
    __syncthreads();
    subm[tid] = lse_all[sidx[tid]];
    f32x4 acc[FMBL][4];
    #pragma unroll
    for (int mb = 0; mb < FMBL; ++mb)
        #pragma unroll
        for (int g = 0; g < 4; ++g) acc[mb][g] = (f32x4){0.f, 0.f, 0.f, 0.f};
    const unsigned short* bth = woh + (size_t)bx * 16 * 2048;
    const unsigned short* btl = wol + (size_t)bx * 16 * 2048;
    const int row = tid >> 2, kq = (tid & 3) * 8;
    const int wave = tid >> 6, lane = tid & 63;
    for (int kt = 0; kt < 16; ++kt){
        *(uint4*)&Bh[row][kq] = *(const uint4*)(bth + (size_t)kt*2048 + (size_t)tid*8);
        *(uint4*)&Bl[row][kq] = *(const uint4*)(btl + (size_t)kt*2048 + (size_t)tid*8);
        #pragma unroll
        for (int mb = 0; mb < FMBL; ++mb){
            const int g = sidx[mb*64 + row];
            *(uint4*)&Ah[row][kq] = *(const uint4*)(hnh + (size_t)g*512 + kt*32 + kq);
            *(uint4*)&Al[row][kq] = *(const uint4*)(hnl + (size_t)g*512 + kt*32 + kq);
            __syncthreads();
            bf16x8 bh = *(const bf16x8*)&Bh[wave*16 + (lane&15)][(lane>>4)*8];
            bf16x8 bl = *(const bf16x8*)&Bl[wave*16 + (lane&15)][(lane>>4)*8];
            #pragma unroll
            for (int gg = 0; gg < 4; ++gg){
                bf16x8 ah = *(const bf16x8*)&Ah[gg*16 + (lane&15)][(lane>>4)*8];
                bf16x8 al = *(const bf16x8*)&Al[gg*16 + (lane&15)][(lane>>4)*8];
                acc[mb][gg] = __builtin_amdgcn_mfma_f32_16x16x32_bf16(ah, bh, acc[mb][gg], 0, 0, 0);
                acc[mb][gg] = __builtin_amdgcn_mfma_f32_16x16x32_bf16(ah, bl, acc[mb][gg], 0, 0, 0);
                acc[mb][gg] = __builtin_amdgcn_mfma_f32_16x16x32_bf16(al, bh, acc[mb][gg], 0, 0, 0);
            }
            __syncthreads();
        }
    }
    const int r = tid >> 2, c0 = (tid & 3) * 16;
    #pragma unroll
    for (int mb = 0; mb < FMBL; ++mb){
        dump_C(acc[mb], Cs, wave, lane);
        __syncthreads();
        const float sub = subm[mb*64 + r];
        float* op = out + (size_t)(mbase + mb*64 + r) * VOC + n0 + c0;
        #pragma unroll
        for (int q = 0; q < 4; ++q){
            float4 bz = *(const float4*)(bo + n0 + c0 + q * 4);
            float4 v;
            v.x = Cs[r][c0 + q*4 + 0] + bz.x - sub;
            v.y = Cs[r][c0 + q*4 + 1] + bz.y - sub;
            v.z = Cs[r][c0 + q*4 + 2] + bz.z - sub;
            v.w = Cs[r][c0 + q*4 + 3] + bz.w - sub;
            *(float4*)(op + q * 4) = v;
        }
        __syncthreads();
    }
}

// =================================================================================
// ======================== fallback (R4, fp32-convert) path =======================
// =================================================================================
__device__ __forceinline__ void mfma_core(
    const float* __restrict__ Abase, const int* __restrict__ ridx, int mbase,
    const float* __restrict__ B, int ldb, int n0,
    unsigned short (&Ah)[64][40], unsigned short (&Al)[64][40],
    unsigned short (&Bh)[64][40], unsigned short (&Bl)[64][40],
    int (&sidx)[64], f32x4 (&acc)[4])
{
    const int tid = threadIdx.x;
    if (tid < 64) sidx[tid] = ridx ? ridx[mbase + tid] : (mbase + tid);
    #pragma unroll
    for (int g = 0; g < 4; ++g) acc[g] = (f32x4){0.f, 0.f, 0.f, 0.f};
    const int wave = tid >> 6, lane = tid & 63;
    const int am = tid >> 2, ak0 = (tid & 3) * 8;
    const int bn = tid & 63, br0 = (tid >> 6) * 8;
    __syncthreads();
    const float* bcol = B + n0 + bn;
    for (int kt = 0; kt < 16; ++kt){
        {
            const float* ap = Abase + (size_t)sidx[am] * HD + kt * 32 + ak0;
            float4 x0 = *(const float4*)ap, x1 = *(const float4*)(ap + 4);
            float xs[8] = {x0.x, x0.y, x0.z, x0.w, x1.x, x1.y, x1.z, x1.w};
            union { unsigned short u[8]; uint4 v; } h8, l8;
            #pragma unroll
            for (int j = 0; j < 8; ++j){
                unsigned short h = f2bf(xs[j]);
                h8.u[j] = h; l8.u[j] = f2bf(xs[j] - bf2f(h));
            }
            *(uint4*)&Ah[am][ak0] = h8.v;
            *(uint4*)&Al[am][ak0] = l8.v;
        }
        {
            const float* bp = bcol + (size_t)(kt * 32 + br0) * ldb;
            union { unsigned short u[8]; uint4 v; } h8, l8;
            #pragma unroll
            for (int j = 0; j < 8; ++j){
                float x = bp[(size_t)j * ldb];
                unsigned short h = f2bf(x);
                h8.u[j] = h; l8.u[j] = f2bf(x - bf2f(h));
            }
            *(uint4*)&Bh[bn][br0] = h8.v;
            *(uint4*)&Bl[bn][br0] = l8.v;
        }
        __syncthreads();
        bf16x8 bh = *(const bf16x8*)&Bh[wave * 16 + (lane & 15)][(lane >> 4) * 8];
        bf16x8 bl = *(const bf16x8*)&Bl[wave * 16 + (lane & 15)][(lane >> 4) * 8];
        #pragma unroll
        for (int g = 0; g < 4; ++g){
            bf16x8 ah = *(const bf16x8*)&Ah[g * 16 + (lane & 15)][(lane >> 4) * 8];
            bf16x8 al = *(const bf16x8*)&Al[g * 16 + (lane & 15)][(lane >> 4) * 8];
            acc[g] = __builtin_amdgcn_mfma_f32_16x16x32_bf16(ah, bh, acc[g], 0, 0, 0);
            acc[g] = __builtin_amdgcn_mfma_f32_16x16x32_bf16(ah, bl, acc[g], 0, 0, 0);
            acc[g] = __builtin_amdgcn_mfma_f32_16x16x32_bf16(al, bh, acc[g], 0, 0, 0);
        }
        __syncthreads();
    }
}

__global__ __launch_bounds__(256) void gates_mfma_kernel(
    const float* __restrict__ E, const int* __restrict__ inp, const float* __restrict__ h_cur,
    const float* __restrict__ W_ih, const float* __restrict__ W_hh,
    const float* __restrict__ b_ih, const float* __restrict__ b_hh,
    float* __restrict__ gbuf)
{
    __shared__ unsigned short Ah[64][40], Al[64][40], Bh[64][40], Bl[64][40];
    __shared__ int sidx[64];
    __shared__ float Cs[64][65];
    const int z = blockIdx.y;
    const int n0 = blockIdx.x * 64;
    const int tid = threadIdx.x;
    f32x4 acc[4];
    mfma_core(z ? h_cur : E, z ? nullptr : inp, 0,
              z ? W_hh : W_ih, G3, n0, Ah, Al, Bh, Bl, sidx, acc);
    dump_C(acc, Cs, tid >> 6, tid & 63);
    __syncthreads();
    const float* bias = z ? b_hh : b_ih;
    const int row = tid >> 2, c0 = (tid & 3) * 16;
    float* gp = gbuf + (size_t)z * BKR * G3 + (size_t)row * G3 + n0 + c0;
    #pragma unroll
    for (int q = 0; q < 4; ++q){
        float4 bz = *(const float4*)(bias + n0 + c0 + q * 4);
        float4 v;
        v.x = Cs[row][c0 + q*4 + 0] + bz.x;
        v.y = Cs[row][c0 + q*4 + 1] + bz.y;
        v.z = Cs[row][c0 + q*4 + 2] + bz.z;
        v.w = Cs[row][c0 + q*4 + 3] + bz.w;
        *(float4*)(gp + q * 4) = v;
    }
}

__global__ __launch_bounds__(256) void logits_topk_kernel(const float* __restrict__ h_new,
    const float* __restrict__ Wo, const float* __restrict__ bo,
    float* __restrict__ pv, int* __restrict__ pc, float* __restrict__ pm, float* __restrict__ ps)
{
    __shared__ unsigned short Ah[64][40], Al[64][40], Bh[64][40], Bl[64][40];
    __shared__ int sidx[64];
    __shared__ float Cs[64][65];
    const int bx = blockIdx.x, n0 = bx * 64;
    const int tid = threadIdx.x;
    f32x4 acc[4];
    mfma_core(h_new, nullptr, 0, Wo, VOC, n0, Ah, Al, Bh, Bl, sidx, acc);
    dump_C(acc, Cs, tid >> 6, tid & 63);
    __syncthreads();
    const int row = tid >> 2, c0 = (tid & 3) * 16;
    float bv[4] = {-INFINITY,-INFINITY,-INFINITY,-INFINITY};
    int bc[4] = {INT_MAX, INT_MAX, INT_MAX, INT_MAX};
    float m = -INFINITY, s = 0.f;
    #pragma unroll
    for (int j = 0; j < 16; ++j){
        float x = Cs[row][c0 + j] + bo[n0 + c0 + j];
        if (x > m){ s = s * expf(m - x) + 1.f; m = x; }
        else s += expf(x - m);
        ins4(bv, bc, x, n0 + c0 + j);
    }
    #pragma unroll
    for (int o = 1; o < 4; o <<= 1){
        float ov[4]; int oc[4];
        #pragma unroll
        for (int q = 0; q < 4; ++q){ ov[q] = __shfl_xor(bv[q], o); oc[q] = __shfl_xor(bc[q], o); }
        #pragma unroll
        for (int q = 0; q < 4; ++q) ins4(bv, bc, ov[q], oc[q]);
        float m2 = __shfl_xor(m, o), s2 = __shfl_xor(s, o);
        float M = fmaxf(m, m2);
        s = s * expf(m - M) + s2 * expf(m2 - M);
        m = M;
    }
    if ((tid & 3) == 0){
        const size_t base = (size_t)row * NE + (size_t)bx * 4;
        #pragma unroll
        for (int q = 0; q < 4; ++q){ pv[base + q] = bv[q]; pc[base + q] = bc[q]; }
        pm[row * NSP + bx] = m; ps[row * NSP + bx] = s;
    }
}

__global__ __launch_bounds__(256) void final_mfma_kernel(const float* __restrict__ h_new_all,
    const int* __restrict__ rmap, const float* __restrict__ lse_all,
    const float* __restrict__ Wo, const float* __restrict__ bo, float* __restrict__ out)
{
    __shared__ unsigned short Ah[64][40], Al[64][40], Bh[64][40], Bl[64][40];
    __shared__ int sidx[64];
    __shared__ float Cs[64][65];
    __shared__ float subm[64];
    const int n0 = blockIdx.x * 64, mb = blockIdx.y * 64;
    const int tid = threadIdx.x;
    f32x4 acc[4];
    mfma_core(h_new_all, rmap, mb, Wo, VOC, n0, Ah, Al, Bh, Bl, sidx, acc);
    dump_C(acc, Cs, tid >> 6, tid & 63);
    if (tid < 64) subm[tid] = lse_all[sidx[tid]];
    __syncthreads();
    const int row = tid >> 2, c0 = (tid & 3) * 16;
    const float sub = subm[row];
    float* op = out + (size_t)(mb + row) * VOC + n0 + c0;
    #pragma unroll
    for (int q = 0; q < 4; ++q){
        float4 bz = *(const float4*)(bo + n0 + c0 + q * 4);
        float4 v;
        v.x = Cs[row][c0 + q*4 + 0] + bz.x - sub;
        v.y = Cs[row][c0 + q*4 + 1] + bz.y - sub;
        v.z = Cs[row][c0 + q*4 + 2] + bz.z - sub;
        v.w = Cs[row][c0 + q*4 + 3] + bz.w - sub;
        *(float4*)(op + q * 4) = v;
    }
}

// =================================================================================
// ============================ shared non-GEMM kernels ============================
// =================================================================================

__global__ void gru_combine_kernel(const float* __restrict__ gbuf, const float* __restrict__ h_cur,
    float* __restrict__ h_new, unsigned short* __restrict__ hnh, unsigned short* __restrict__ hnl)
{
    int x = blockIdx.x * 256 + threadIdx.x;
    int i = x >> 9, j = x & 511;
    const float* gi = gbuf + (size_t)i * G3;
    const float* gh = gbuf + (size_t)BKR * G3 + (size_t)i * G3;
    float ir = gi[j], iz = gi[j + 512], inn = gi[j + 1024];
    float hr = gh[j], hz = gh[j + 512], hnv = gh[j + 1024];
    float r  = 1.f / (1.f + expf(-(ir + hr)));
    float zz = 1.f / (1.f + expf(-(iz + hz)));
    float n  = tanhf(inn + r * hnv);
    float v = (1.f - zz) * n + zz * h_cur[x];
    h_new[x] = v;
    if (hnh){
        unsigned short h = f2bf(v);
        hnh[x] = h; hnl[x] = f2bf(v - bf2f(h));
    }
}

__global__ __launch_bounds__(256) void topk_phase_b(
    const float* __restrict__ pv, const int* __restrict__ pc,
    const float* __restrict__ pm, const float* __restrict__ ps,
    int t,
    float* __restrict__ scores_all, int* __restrict__ preds_all, int* __restrict__ syms_all,
    float* __restrict__ ss, int* __restrict__ inp, float* __restrict__ lse_all,
    const float* __restrict__ h_new, float* __restrict__ h_cur,
    const float* __restrict__ E,
    unsigned short* __restrict__ hch, unsigned short* __restrict__ hcl,
    unsigned short* __restrict__ eih, unsigned short* __restrict__ eil)
{
    const int b = blockIdx.x, tid = threadIdx.x;
    const int wave = tid >> 6, lane = tid & 63;
    const int row = b * KBEAM + wave;

    float bv[4] = {-INFINITY,-INFINITY,-INFINITY,-INFINITY};
    int bc[4] = {INT_MAX, INT_MAX, INT_MAX, INT_MAX};
    for (int e = lane; e < NE; e += 64)
        ins4(bv, bc, pv[(size_t)row * NE + e], pc[(size_t)row * NE + e]);
    #pragma unroll
    for (int o = 1; o < 64; o <<= 1){
        float ov[4]; int oc[4];
        #pragma unroll
        for (int q = 0; q < 4; ++q){ ov[q] = __shfl_xor(bv[q], o); oc[q] = __shfl_xor(bc[q], o); }
        #pragma unroll
        for (int q = 0; q < 4; ++q) ins4(bv, bc, ov[q], oc[q]);
    }
    float m = -INFINITY, s = 0.f;
    for (int e = lane; e < NSP; e += 64){
        float m2 = pm[row * NSP + e], s2 = ps[row * NSP + e];
        float M = fmaxf(m, m2);
        s = s * expf(m - M) + s2 * expf(m2 - M);
        m = M;
    }
    #pragma unroll
    for (int o = 1; o < 64; o <<= 1){
        float m2 = __shfl_xor(m, o), s2 = __shfl_xor(s, o);
        float M = fmaxf(m, m2);
        s = s * expf(m - M) + s2 * expf(m2 - M);
        m = M;
    }
    __shared__ float rtv[KBEAM][4]; __shared__ int rtc[KBEAM][4];
    __shared__ float rlse[KBEAM];
    if (lane == 0){
        #pragma unroll
        for (int q = 0; q < 4; ++q){ rtv[wave][q] = bv[q]; rtc[wave][q] = bc[q]; }
        rlse[wave] = m + logf(s);
    }
    __syncthreads();
    __shared__ int spred[KBEAM]; __shared__ int ssym[KBEAM];
    if (tid == 0){
        float gv[4] = {-INFINITY,-INFINITY,-INFINITY,-INFINITY};
        int gc[4] = {INT_MAX, INT_MAX, INT_MAX, INT_MAX};
        #pragma unroll
        for (int kl = 0; kl < KBEAM; ++kl){
            const int r2 = b * KBEAM + kl;
            float lse = rlse[kl];
            lse_all[t * BKR + r2] = lse;
            float off = ss[r2] - lse;
            if (off == -INFINITY){
                #pragma unroll
                for (int q = 0; q < 4; ++q) ins4(gv, gc, -INFINITY, kl * VOC + q);
            } else {
                #pragma unroll
                for (int q = 0; q < 4; ++q) ins4(gv, gc, rtv[kl][q] + off, kl * VOC + rtc[kl][q]);
            }
        }
        #pragma unroll
        for (int u = 0; u < KBEAM; ++u){
            int cand = gc[u]; float val = gv[u];
            int sym = cand % VOC; int pg = b * KBEAM + cand / VOC;
            int slot = b * KBEAM + u;
            scores_all[t * BKR + slot] = val;
            syms_all[t * BKR + slot] = sym;
            preds_all[t * BKR + slot] = pg;
            ss[slot] = (sym == EOS_TOK) ? -INFINITY : val;
            inp[slot] = sym;
            spred[u] = pg; ssym[u] = sym;
        }
    }
    __syncthreads();
    for (int x = tid; x < KBEAM * HD; x += 256){
        int u = x >> 9, j = x & 511;
        const int idx = (b * KBEAM + u) * HD + j;
        float v = h_new[spred[u] * HD + j];
        h_cur[idx] = v;
        if (hch){
            unsigned short h = f2bf(v);
            hch[idx] = h; hcl[idx] = f2bf(v - bf2f(h));
            float e = E[(size_t)ssym[u] * HD + j];
            unsigned short eh = f2bf(e);
            eih[idx] = eh; eil[idx] = f2bf(e - bf2f(eh));
        }
    }
}

__global__ void init_kernel(const float* __restrict__ enc_h, const float* __restrict__ E,
    float* __restrict__ h_cur, float* __restrict__ ss, int* __restrict__ inp,
    unsigned short* __restrict__ hch, unsigned short* __restrict__ hcl,
    unsigned short* __restrict__ eih, unsigned short* __restrict__ eil)
{
    const int i = blockIdx.x;
    for (int j = threadIdx.x; j < HD; j += blockDim.x){
        float v = enc_h[(i & (BATCH - 1)) * HD + j];
        h_cur[i * HD + j] = v;
        if (hch){
            const int idx = i * HD + j;
            unsigned short h = f2bf(v);
            hch[idx] = h; hcl[idx] = f2bf(v - bf2f(h));
            float e = E[(size_t)SOS_TOK * HD + j];
            unsigned short eh = f2bf(e);
            eih[idx] = eh; eil[idx] = f2bf(e - bf2f(eh));
        }
    }
    if (i == 0 && threadIdx.x < BKR){
        ss[threadIdx.x] = ((threadIdx.x & (KBEAM - 1)) == 0) ? 0.f : -INFINITY;
        inp[threadIdx.x] = SOS_TOK;
    }
}

// ================= backtrack (single block, LDS-staged, parallel) =================
__global__ __launch_bounds__(256) void backtrack_kernel(
    const float* __restrict__ scores_all, const int* __restrict__ preds_all, const int* __restrict__ syms_all,
    const float* __restrict__ h_new_all, float* __restrict__ hn_fin,
    int* __restrict__ rmap, float* __restrict__ out)
{
    __shared__ int   l_syms[T_STEPS*BKR];
    __shared__ int   l_preds[T_STEPS*BKR];
    __shared__ float l_scores[T_STEPS*BKR];
    __shared__ int   outrow_s[T_STEPS*BKR];
    __shared__ int   cursym_s[T_STEPS*BKR];
    __shared__ int tpred[64]; __shared__ float sfin[64]; __shared__ int lensq[64];
    __shared__ int eosf[BATCH];
    __shared__ int orow[64], csym[64], npred_s[64];
    __shared__ int cp_slot[64], cp_src[64]; __shared__ int nc_b[BATCH];
    __shared__ int reidx[64];
    const int tid = threadIdx.x;

    for (int x = tid; x < T_STEPS*BKR; x += 256){
        l_syms[x]   = syms_all[x];
        l_preds[x]  = preds_all[x];
        l_scores[x] = scores_all[x];
    }
    for (int x = tid; x < BKR*HD; x += 256) hn_fin[x] = 0.f;
    __syncthreads();

    if (tid < BATCH){
        const int b = tid;
        float v[KBEAM]; int used[KBEAM];
        #pragma unroll
        for (int k = 0; k < KBEAM; ++k){ v[k] = l_scores[(T_STEPS-1)*BKR + b*KBEAM + k]; used[k] = 0; }
        #pragma unroll
        for (int u = 0; u < KBEAM; ++u){
            int best = -1; float bvv = 0.f;
            #pragma unroll
            for (int k = 0; k < KBEAM; ++k) if (!used[k] && (best < 0 || v[k] > bvv)){ best = k; bvv = v[k]; }
            used[best] = 1;
            tpred[b*KBEAM+u] = b*KBEAM + best;
            sfin[b*KBEAM+u] = bvv;
            lensq[b*KBEAM+u] = T_STEPS;
        }
        eosf[b] = 0;
    }
    __syncthreads();

    for (int t = T_STEPS-1; t >= 0; --t){
        if (tid < 64){
            int tp = tpred[tid];
            orow[tid]    = tp;
            csym[tid]    = l_syms[t*BKR + tp];
            npred_s[tid] = l_preds[t*BKR + tp];
        }
        __syncthreads();
        if (tid < BATCH){
            const int b = tid;
            int eos[KBEAM]; int cnt = 0;
            #pragma unroll
            for (int k = 0; k < KBEAM; ++k) eos[k] = (l_syms[t*BKR + b*KBEAM + k] == EOS_TOK);
            int nc = 0;
            #pragma unroll
            for (int k = 0; k < KBEAM; ++k) if (eos[k]){
                int higher = 0;
                #pragma unroll
                for (int k2 = k+1; k2 < KBEAM; ++k2) higher += eos[k2];
                int occ = eosf[b] + higher;
                int rk = KBEAM - (occ % KBEAM) - 1;
                int slot = b*KBEAM + rk;
                int j = b*KBEAM + k;
                npred_s[slot] = l_preds[t*BKR + j];
                orow[slot]    = j;
                csym[slot]    = l_syms[t*BKR + j];
                sfin[slot]    = l_scores[t*BKR + j];
                lensq[slot]   = t + 1;
                cp_slot[b*KBEAM + nc] = slot;
                cp_src[b*KBEAM + nc]  = l_preds[t*BKR + j];
                ++nc; ++cnt;
            }
            nc_b[b] = nc;
            eosf[b] += cnt;
        }
        __syncthreads();
        if (tid < 64){
            outrow_s[t*BKR + tid] = orow[tid];
            cursym_s[t*BKR + tid] = csym[tid];
            tpred[tid] = npred_s[tid];
        }
        {
            const int e = tid >> 2;
            const int eb = e >> 2, eq = e & 3;
            if (eq < nc_b[eb]){
                const int slot = cp_slot[eb*KBEAM + eq];
                const int src  = cp_src[eb*KBEAM + eq];
                const float4* sp = (const float4*)(h_new_all + (size_t)(t*BKR + src)*HD);
                float4* dp = (float4*)(hn_fin + (size_t)slot*HD);
                for (int j = (tid & 3); j < HD/4; j += 4) dp[j] = sp[j];
            }
        }
        __syncthreads();
    }

    if (tid < BATCH){
        const int b = tid;
        float v[KBEAM]; int used[KBEAM];
        #pragma unroll
        for (int k = 0; k < KBEAM; ++k){ v[k] = sfin[b*KBEAM+k]; used[k] = 0; }
        #pragma unroll
        for (int u = 0; u < KBEAM; ++u){
            int best = -1; float bvv = 0.f;
            #pragma unroll
            for (int k = 0; k < KBEAM; ++k) if (!used[k] && (best < 0 || v[k] > bvv)){ best = k; bvv = v[k]; }
            used[best] = 1;
            reidx[b*KBEAM+u] = best;
            out[O_SSRT + b*KBEAM + u] = bvv;
            out[O_LENS + b*KBEAM + u] = (float)lensq[b*KBEAM + best];
        }
    }
    __syncthreads();
    for (int x = tid; x < T_STEPS*BATCH; x += 256){
        int t2 = x >> 4, b = x & 15;
        rmap[x] = t2*BKR + outrow_s[t2*BKR + b*KBEAM + reidx[b*KBEAM]];
    }
    for (int x = tid; x < T_STEPS*BKR; x += 256){
        int t2 = x >> 6, rem = x & 63, b = rem >> 2, k = rem & 3;
        out[O_SEQS + x] = (float)cursym_s[t2*BKR + b*KBEAM + reidx[b*KBEAM + k]];
    }
    for (int x = tid; x < BATCH*HD; x += 256){
        int b = x >> 9, j = x & 511;
        out[O_HID + x] = hn_fin[(b*KBEAM + reidx[b*KBEAM])*HD + j];
    }
}

extern "C" void kernel_launch(void* const* d_in, const int* in_sizes, int n_in,
                              void* d_out, int out_size, void* d_ws, size_t ws_size,
                              hipStream_t stream)
{
    const float* enc_h = (const float*)d_in[0];
    const float* E     = (const float*)d_in[1];
    const float* W_ih  = (const float*)d_in[2];
    const float* W_hh  = (const float*)d_in[3];
    const float* b_ih  = (const float*)d_in[4];
    const float* b_hh  = (const float*)d_in[5];
    const float* Wo    = (const float*)d_in[6];
    const float* bo    = (const float*)d_in[7];
    float* out = (float*)d_out;

    float* w = (float*)d_ws;
    float* h_cur      = w + OFF_HCUR;
    float* gbuf       = w + OFF_GBUF;
    float* h_new_all  = w + OFF_HNEW;
    float* lse_all    = w + OFF_LSE;
    float* ss         = w + OFF_SS;
    float* scores_all = w + OFF_SCORES;
    float* hn_fin     = w + OFF_HNFIN;
    float* pv         = w + OFF_PV;
    float* pm         = w + OFF_PM;
    float* ps         = w + OFF_PS;
    int* wi         = (int*)(w + OFF_FEND);
    int* inp        = wi + IOFF_INP;
    int* preds_all  = wi + IOFF_PREDS;
    int* syms_all   = wi + IOFF_SYMS;
    int* rmap       = wi + IOFF_RMAP;
    int* pc         = wi + IOFF_PC;
    unsigned short* sb = (unsigned short*)(wi + IOFF_END);
    unsigned short* woh = sb + S_WOH;
    unsigned short* wol = sb + S_WOL;
    unsigned short* wgh = sb + S_WGH;
    unsigned short* wgl = sb + S_WGL;
    unsigned short* hnh = sb + S_HNH;
    unsigned short* hnl = sb + S_HNL;
    unsigned short* hch = sb + S_HCH;
    unsigned short* hcl = sb + S_HCL;
    unsigned short* eih = sb + S_EIH;
    unsigned short* eil = sb + S_EIL;

    const size_t NEED = (size_t)OFF_FEND*4 + (size_t)IOFF_END*4 + (size_t)S_END*2;
    const bool pre = (ws_size >= NEED);

    init_kernel<<<dim3(BKR), 256, 0, stream>>>(enc_h, E, h_cur, ss, inp,
        pre ? hch : nullptr, hcl, eih, eil);
    if (pre){
        prepack_kernel<<<dim3(NSP, 16), 256, 0, stream>>>(Wo, VOC, woh, wol);
        prepack_kernel<<<dim3(NBG, 16), 256, 0, stream>>>(W_ih, G3, wgh, wgl);
        prepack_kernel<<<dim3(NBG, 16), 256, 0, stream>>>(W_hh, G3,
            wgh + (size_t)NBG*16*2048, wgl + (size_t)NBG*16*2048);
    }
    for (int t = 0; t < T_STEPS; ++t){
        float* h_new_t = h_new_all + (size_t)t * BKR * HD;
        unsigned short* hnh_t = hnh + (size_t)t * BKR * HD;
        unsigned short* hnl_t = hnl + (size_t)t * BKR * HD;
        if (pre){
            gates_pre_kernel<<<dim3(NBG, 2), 256, 0, stream>>>(eih, eil, hch, hcl,
                wgh, wgl, b_ih, b_hh, gbuf);
        } else {
            gates_mfma_kernel<<<dim3(NBG, 2), 256, 0, stream>>>(E, inp, h_cur, W_ih, W_hh, b_ih, b_hh, gbuf);
        }
        gru_combine_kernel<<<dim3(BKR*HD/256), 256, 0, stream>>>(gbuf, h_cur, h_new_t,
            pre ? hnh_t : nullptr, hnl_t);
        if (pre){
            logits_pre_kernel<<<dim3(NSP), 256, 0, stream>>>(hnh_t, hnl_t, woh, wol, bo, pv, pc, pm, ps);
        } else {
            logits_topk_kernel<<<dim3(NSP), 256, 0, stream>>>(h_new_t, Wo, bo, pv, pc, pm, ps);
        }
        topk_phase_b<<<dim3(BATCH), 256, 0, stream>>>(pv, pc, pm, ps, t, scores_all, preds_all, syms_all,
            ss, inp, lse_all, h_new_t, h_cur, E,
            pre ? hch : nullptr, hcl, eih, eil);
    }
    backtrack_kernel<<<dim3(1), 256, 0, stream>>>(scores_all, preds_all, syms_all, h_new_all, hn_fin,
                                                  rmap, out);
    if (pre){
        final_pre_kernel<<<dim3(NSP, (T_STEPS*BATCH)/(64*FMBL)), 256, 0, stream>>>(
            hnh, hnl, rmap, lse_all, woh, wol, bo, out);
    } else {
        final_mfma_kernel<<<dim3(NSP, T_STEPS*BATCH/64), 256, 0, stream>>>(h_new_all, rmap, lse_all, Wo, bo, out);
    }
}